// Round 1
// baseline (4328.765 us; speedup 1.0000x reference)
//
#include <hip/hip_runtime.h>
#include <hip/hip_bf16.h>

#define NN 50000
#define NE 1600000
#define ETOT (NE + NN)   // 1,650,000 (self-loops appended)

__device__ __forceinline__ float leaky02(float x) { return x > 0.f ? x : 0.2f * x; }

__device__ __forceinline__ void atomicMaxF(float* addr, float val) {
    if (val >= 0.f) atomicMax((int*)addr, __float_as_int(val));
    else            atomicMin((unsigned int*)addr, __float_as_uint(val));
}

// ---------------- GEMM: C[M,N] = act(A[M,128] @ B[128,N] + bias) ----------------
// 64x64 tile, 256 threads, 4x4 microtile, BK=64.
template<int ACT>
__global__ void gemm_k128(const float* __restrict__ A, const float* __restrict__ B,
                          const float* __restrict__ bias, float* __restrict__ C,
                          int M, int N) {
    __shared__ float As[64][68];
    __shared__ float Bs[64][68];
    const int tid = threadIdx.x;
    const int ty = tid >> 4, tx = tid & 15;
    const int row0 = blockIdx.x * 64;
    const int col0 = blockIdx.y * 64;
    float acc[4][4] = {};
    for (int kk = 0; kk < 128; kk += 64) {
        #pragma unroll
        for (int t = 0; t < 4; ++t) {
            int f = tid + t * 256;            // 1024 float4 slots
            int r = f >> 4;
            int c4 = (f & 15) << 2;
            int gr = row0 + r;
            float4 v = make_float4(0.f, 0.f, 0.f, 0.f);
            if (gr < M) v = *(const float4*)&A[(long)gr * 128 + kk + c4];
            As[r][c4] = v.x; As[r][c4 + 1] = v.y; As[r][c4 + 2] = v.z; As[r][c4 + 3] = v.w;
        }
        #pragma unroll
        for (int t = 0; t < 4; ++t) {
            int f = tid + t * 256;
            int r = f >> 4;
            int c4 = (f & 15) << 2;
            float4 v = *(const float4*)&B[(long)(kk + r) * N + col0 + c4];
            Bs[r][c4] = v.x; Bs[r][c4 + 1] = v.y; Bs[r][c4 + 2] = v.z; Bs[r][c4 + 3] = v.w;
        }
        __syncthreads();
        #pragma unroll
        for (int k = 0; k < 64; ++k) {
            float a0 = As[ty * 4 + 0][k];
            float a1 = As[ty * 4 + 1][k];
            float a2 = As[ty * 4 + 2][k];
            float a3 = As[ty * 4 + 3][k];
            float4 b = *(const float4*)&Bs[k][tx * 4];
            acc[0][0] += a0 * b.x; acc[0][1] += a0 * b.y; acc[0][2] += a0 * b.z; acc[0][3] += a0 * b.w;
            acc[1][0] += a1 * b.x; acc[1][1] += a1 * b.y; acc[1][2] += a1 * b.z; acc[1][3] += a1 * b.w;
            acc[2][0] += a2 * b.x; acc[2][1] += a2 * b.y; acc[2][2] += a2 * b.z; acc[2][3] += a2 * b.w;
            acc[3][0] += a3 * b.x; acc[3][1] += a3 * b.y; acc[3][2] += a3 * b.z; acc[3][3] += a3 * b.w;
        }
        __syncthreads();
    }
    #pragma unroll
    for (int i = 0; i < 4; ++i) {
        int gr = row0 + ty * 4 + i;
        if (gr >= M) continue;
        #pragma unroll
        for (int j = 0; j < 4; ++j) {
            int gc = col0 + tx * 4 + j;
            float v = acc[i][j] + (bias ? bias[gc] : 0.f);
            if (ACT == 1) v = v > 0.f ? v : 0.f;
            C[(long)gr * N + gc] = v;
        }
    }
}

// ---------------- attention coefficients: a[n,h] = sum_c h[n,h*C+c]*att[h*C+c] ----
template<int C>
__global__ void att_reduce(const float* __restrict__ h, const float* __restrict__ attS,
                           const float* __restrict__ attD, float* __restrict__ aS,
                           float* __restrict__ aD) {
    int wave = (int)((blockIdx.x * (long)blockDim.x + threadIdx.x) >> 6);
    int lane = threadIdx.x & 63;
    if (wave >= NN) return;
    const float* row = h + (long)wave * (4 * C);
    #pragma unroll
    for (int hh = 0; hh < 4; ++hh) {
        float ps = 0.f, pd = 0.f;
        for (int c = lane; c < C; c += 64) {
            float v = row[hh * C + c];
            ps += v * attS[hh * C + c];
            pd += v * attD[hh * C + c];
        }
        #pragma unroll
        for (int off = 32; off; off >>= 1) {
            ps += __shfl_xor(ps, off);
            pd += __shfl_xor(pd, off);
        }
        if (lane == 0) { aS[wave * 4 + hh] = ps; aD[wave * 4 + hh] = pd; }
    }
}

// ---------------- edge passes ----------------
__global__ void edge_max_k(const int* __restrict__ srcA, const int* __restrict__ dstA,
                           const float* __restrict__ aS, const float* __restrict__ aD,
                           float* __restrict__ m) {
    int e = blockIdx.x * blockDim.x + threadIdx.x;
    if (e >= ETOT) return;
    int s, d;
    if (e < NE) { s = srcA[e]; d = dstA[e]; } else { s = d = e - NE; }
    float4 vs = *(const float4*)&aS[s * 4];
    float4 vd = *(const float4*)&aD[d * 4];
    atomicMaxF(&m[d * 4 + 0], leaky02(vs.x + vd.x));
    atomicMaxF(&m[d * 4 + 1], leaky02(vs.y + vd.y));
    atomicMaxF(&m[d * 4 + 2], leaky02(vs.z + vd.z));
    atomicMaxF(&m[d * 4 + 3], leaky02(vs.w + vd.w));
}

__global__ void edge_expsum_k(const int* __restrict__ srcA, const int* __restrict__ dstA,
                              const float* __restrict__ aS, const float* __restrict__ aD,
                              const float* __restrict__ m, float* __restrict__ ssum,
                              float* __restrict__ exb) {
    int e = blockIdx.x * blockDim.x + threadIdx.x;
    if (e >= ETOT) return;
    int s, d;
    if (e < NE) { s = srcA[e]; d = dstA[e]; } else { s = d = e - NE; }
    float4 vs = *(const float4*)&aS[s * 4];
    float4 vd = *(const float4*)&aD[d * 4];
    float4 mm = *(const float4*)&m[d * 4];
    float4 ex;
    ex.x = __expf(leaky02(vs.x + vd.x) - mm.x);
    ex.y = __expf(leaky02(vs.y + vd.y) - mm.y);
    ex.z = __expf(leaky02(vs.z + vd.z) - mm.z);
    ex.w = __expf(leaky02(vs.w + vd.w) - mm.w);
    *(float4*)&exb[(long)e * 4] = ex;
    atomicAdd(&ssum[d * 4 + 0], ex.x);
    atomicAdd(&ssum[d * 4 + 1], ex.y);
    atomicAdd(&ssum[d * 4 + 2], ex.z);
    atomicAdd(&ssum[d * 4 + 3], ex.w);
}

// one wave per edge; layer-1 scatter (concat, C=32)
__global__ void scatter1_k(const int* __restrict__ srcA, const int* __restrict__ dstA,
                           const float* __restrict__ exb, const float* __restrict__ ssum,
                           const float* __restrict__ h1, float* __restrict__ out) {
    long gt = blockIdx.x * (long)blockDim.x + threadIdx.x;
    int wid = (int)(gt >> 6);
    int lane = threadIdx.x & 63;
    if (wid >= ETOT) return;
    int s, d;
    if (wid < NE) { s = srcA[wid]; d = dstA[wid]; } else { s = d = wid - NE; }
    float4 e4 = *(const float4*)&exb[(long)wid * 4];
    float4 s4 = *(const float4*)&ssum[d * 4];
    float w0 = e4.x / (s4.x + 1e-16f);
    float w1 = e4.y / (s4.y + 1e-16f);
    float w2 = e4.z / (s4.z + 1e-16f);
    float w3 = e4.w / (s4.w + 1e-16f);
    int c = lane * 2;
    float2 hv = *(const float2*)&h1[(long)s * 128 + c];
    float w = (c < 32) ? w0 : (c < 64) ? w1 : (c < 96) ? w2 : w3;
    atomicAdd(&out[(long)d * 128 + c], w * hv.x);
    atomicAdd(&out[(long)d * 128 + c + 1], w * hv.y);
}

// layer-2 scatter (head-mean folded in, C=128)
__global__ void scatter2_k(const int* __restrict__ srcA, const int* __restrict__ dstA,
                           const float* __restrict__ exb, const float* __restrict__ ssum,
                           const float* __restrict__ h2, float* __restrict__ out) {
    long gt = blockIdx.x * (long)blockDim.x + threadIdx.x;
    int wid = (int)(gt >> 6);
    int lane = threadIdx.x & 63;
    if (wid >= ETOT) return;
    int s, d;
    if (wid < NE) { s = srcA[wid]; d = dstA[wid]; } else { s = d = wid - NE; }
    float4 e4 = *(const float4*)&exb[(long)wid * 4];
    float4 s4 = *(const float4*)&ssum[d * 4];
    float w0 = 0.25f * e4.x / (s4.x + 1e-16f);
    float w1 = 0.25f * e4.y / (s4.y + 1e-16f);
    float w2 = 0.25f * e4.z / (s4.z + 1e-16f);
    float w3 = 0.25f * e4.w / (s4.w + 1e-16f);
    int c = lane * 2;
    const float* row = h2 + (long)s * 512;
    float2 v0 = *(const float2*)&row[c];
    float2 v1 = *(const float2*)&row[128 + c];
    float2 v2 = *(const float2*)&row[256 + c];
    float2 v3 = *(const float2*)&row[384 + c];
    float ax = w0 * v0.x + w1 * v1.x + w2 * v2.x + w3 * v3.x;
    float ay = w0 * v0.y + w1 * v1.y + w2 * v2.y + w3 * v3.y;
    atomicAdd(&out[(long)d * 128 + c], ax);
    atomicAdd(&out[(long)d * 128 + c + 1], ay);
}

// bias + BN(eval) + ELU, in place
__global__ void bn_elu_k(float* __restrict__ x, const float* __restrict__ b1,
                         const float* __restrict__ g, const float* __restrict__ be) {
    int i = blockIdx.x * blockDim.x + threadIdx.x;
    if (i >= NN * 128) return;
    int c = i & 127;
    float v = (x[i] + b1[c]) * 0.9999950000374997f * g[c] + be[c];
    x[i] = v > 0.f ? v : (__expf(v) - 1.f);
}

__global__ void colsum_k(const float* __restrict__ x, float* __restrict__ cs) {
    int c = threadIdx.x;  // 128
    float acc = 0.f;
    for (int r = blockIdx.x; r < NN; r += gridDim.x)
        acc += x[(long)r * 128 + c];
    atomicAdd(&cs[c], acc);
}

__global__ void final_k(const float* __restrict__ cs, const float* __restrict__ bias2,
                        const float* __restrict__ W, const float* __restrict__ ob,
                        float* __restrict__ out) {
    __shared__ float xm[128];
    int c = threadIdx.x;
    xm[c] = cs[c] * (1.f / NN) + bias2[c];
    __syncthreads();
    float acc = ob[c];
    for (int k = 0; k < 128; ++k) acc += xm[k] * W[k * 128 + c];
    out[c] = acc > 0.f ? acc : 0.f;
}

extern "C" void kernel_launch(void* const* d_in, const int* in_sizes, int n_in,
                              void* d_out, int out_size, void* d_ws, size_t ws_size,
                              hipStream_t stream) {
    const float* x0  = (const float*)d_in[0];
    const int*   ei  = (const int*)d_in[1];
    const float* pW  = (const float*)d_in[2];
    const float* pb  = (const float*)d_in[3];
    const float* W1  = (const float*)d_in[4];
    const float* as1 = (const float*)d_in[5];
    const float* ad1 = (const float*)d_in[6];
    const float* b1  = (const float*)d_in[7];
    const float* bg  = (const float*)d_in[8];
    const float* bb  = (const float*)d_in[9];
    const float* W2  = (const float*)d_in[10];
    const float* as2 = (const float*)d_in[11];
    const float* ad2 = (const float*)d_in[12];
    const float* b2  = (const float*)d_in[13];
    const float* oW  = (const float*)d_in[14];
    const float* ob  = (const float*)d_in[15];
    float* out = (float*)d_out;

    float* ws = (float*)d_ws;
    float* x1 = ws; ws += 6400000;       // proj output
    float* h1 = ws; ws += 6400000;       // layer-1 features
    float* x2 = ws; ws += 6400000;       // layer-1 aggregate -> BN/ELU in place
    float* h2 = ws; ws += 25600000;      // layer-2 features [N,512]
    float* o2 = ws; ws += 6400000;       // layer-2 aggregate
    float* aS = ws; ws += 200000;
    float* aD = ws; ws += 200000;
    float* mb = ws; ws += 200000;
    float* sb = ws; ws += 200000;
    float* ex = ws; ws += 6600000;
    float* cs = ws; ws += 128;

    const int* srcA = ei;
    const int* dstA = ei + NE;

    hipMemsetAsync(x2, 0, (size_t)6400000 * 4, stream);
    hipMemsetAsync(o2, 0, (size_t)6400000 * 4, stream);
    hipMemsetAsync(mb, 0xFF, (size_t)200000 * 4, stream);
    hipMemsetAsync(sb, 0, (size_t)200000 * 4, stream);
    hipMemsetAsync(cs, 0, (size_t)128 * 4, stream);

    dim3 blk(256);
    const int egrid = (ETOT + 255) / 256;
    const int sgrid = (ETOT + 3) / 4;         // 4 waves / block

    gemm_k128<1><<<dim3(782, 2), blk, 0, stream>>>(x0, pW, pb, x1, NN, 128);
    gemm_k128<0><<<dim3(782, 2), blk, 0, stream>>>(x1, W1, nullptr, h1, NN, 128);
    att_reduce<32><<<12500, blk, 0, stream>>>(h1, as1, ad1, aS, aD);
    edge_max_k<<<egrid, blk, 0, stream>>>(srcA, dstA, aS, aD, mb);
    edge_expsum_k<<<egrid, blk, 0, stream>>>(srcA, dstA, aS, aD, mb, sb, ex);
    scatter1_k<<<sgrid, blk, 0, stream>>>(srcA, dstA, ex, sb, h1, x2);
    bn_elu_k<<<(NN * 128 + 255) / 256, blk, 0, stream>>>(x2, b1, bg, bb);
    gemm_k128<0><<<dim3(782, 8), blk, 0, stream>>>(x2, W2, nullptr, h2, NN, 512);
    att_reduce<128><<<12500, blk, 0, stream>>>(h2, as2, ad2, aS, aD);
    hipMemsetAsync(mb, 0xFF, (size_t)200000 * 4, stream);
    hipMemsetAsync(sb, 0, (size_t)200000 * 4, stream);
    edge_max_k<<<egrid, blk, 0, stream>>>(srcA, dstA, aS, aD, mb);
    edge_expsum_k<<<egrid, blk, 0, stream>>>(srcA, dstA, aS, aD, mb, sb, ex);
    scatter2_k<<<sgrid, blk, 0, stream>>>(srcA, dstA, ex, sb, h2, o2);
    colsum_k<<<256, 128, 0, stream>>>(o2, cs);
    final_k<<<1, 128, 0, stream>>>(cs, b2, oW, ob, out);
}

// Round 2
// 2403.366 us; speedup vs baseline: 1.8011x; 1.8011x over previous
//
#include <hip/hip_runtime.h>
#include <hip/hip_bf16.h>

#define NN 50000
#define NE 1600000
#define ETOT (NE + NN)   // 1,650,000 (self-loops appended)
#define BN_K 0.9999950000374997f

__device__ __forceinline__ float leaky02(float x) { return x > 0.f ? x : 0.2f * x; }

__device__ __forceinline__ void atomicMaxF(float* addr, float val) {
    if (val >= 0.f) atomicMax((int*)addr, __float_as_int(val));
    else            atomicMin((unsigned int*)addr, __float_as_uint(val));
}

// ---------------- GEMM: C[M,N] = act(A[M,128] @ B[128,N] + bias) ----------------
template<int ACT>
__global__ void gemm_k128(const float* __restrict__ A, const float* __restrict__ B,
                          const float* __restrict__ bias, float* __restrict__ C,
                          int M, int N) {
    __shared__ float As[64][68];
    __shared__ float Bs[64][68];
    const int tid = threadIdx.x;
    const int ty = tid >> 4, tx = tid & 15;
    const int row0 = blockIdx.x * 64;
    const int col0 = blockIdx.y * 64;
    float acc[4][4] = {};
    for (int kk = 0; kk < 128; kk += 64) {
        #pragma unroll
        for (int t = 0; t < 4; ++t) {
            int f = tid + t * 256;
            int r = f >> 4;
            int c4 = (f & 15) << 2;
            int gr = row0 + r;
            float4 v = make_float4(0.f, 0.f, 0.f, 0.f);
            if (gr < M) v = *(const float4*)&A[(long)gr * 128 + kk + c4];
            As[r][c4] = v.x; As[r][c4 + 1] = v.y; As[r][c4 + 2] = v.z; As[r][c4 + 3] = v.w;
        }
        #pragma unroll
        for (int t = 0; t < 4; ++t) {
            int f = tid + t * 256;
            int r = f >> 4;
            int c4 = (f & 15) << 2;
            float4 v = *(const float4*)&B[(long)(kk + r) * N + col0 + c4];
            Bs[r][c4] = v.x; Bs[r][c4 + 1] = v.y; Bs[r][c4 + 2] = v.z; Bs[r][c4 + 3] = v.w;
        }
        __syncthreads();
        #pragma unroll
        for (int k = 0; k < 64; ++k) {
            float a0 = As[ty * 4 + 0][k];
            float a1 = As[ty * 4 + 1][k];
            float a2 = As[ty * 4 + 2][k];
            float a3 = As[ty * 4 + 3][k];
            float4 b = *(const float4*)&Bs[k][tx * 4];
            acc[0][0] += a0 * b.x; acc[0][1] += a0 * b.y; acc[0][2] += a0 * b.z; acc[0][3] += a0 * b.w;
            acc[1][0] += a1 * b.x; acc[1][1] += a1 * b.y; acc[1][2] += a1 * b.z; acc[1][3] += a1 * b.w;
            acc[2][0] += a2 * b.x; acc[2][1] += a2 * b.y; acc[2][2] += a2 * b.z; acc[2][3] += a2 * b.w;
            acc[3][0] += a3 * b.x; acc[3][1] += a3 * b.y; acc[3][2] += a3 * b.z; acc[3][3] += a3 * b.w;
        }
        __syncthreads();
    }
    #pragma unroll
    for (int i = 0; i < 4; ++i) {
        int gr = row0 + ty * 4 + i;
        if (gr >= M) continue;
        #pragma unroll
        for (int j = 0; j < 4; ++j) {
            int gc = col0 + tx * 4 + j;
            float v = acc[i][j] + (bias ? bias[gc] : 0.f);
            if (ACT == 1) v = v > 0.f ? v : 0.f;
            C[(long)gr * N + gc] = v;
        }
    }
}

// ---------------- attention coefficients ----------------
template<int C>
__global__ void att_reduce(const float* __restrict__ h, const float* __restrict__ attS,
                           const float* __restrict__ attD, float* __restrict__ aS,
                           float* __restrict__ aD) {
    int wave = (int)((blockIdx.x * (long)blockDim.x + threadIdx.x) >> 6);
    int lane = threadIdx.x & 63;
    if (wave >= NN) return;
    const float* row = h + (long)wave * (4 * C);
    #pragma unroll
    for (int hh = 0; hh < 4; ++hh) {
        float ps = 0.f, pd = 0.f;
        for (int c = lane; c < C; c += 64) {
            float v = row[hh * C + c];
            ps += v * attS[hh * C + c];
            pd += v * attD[hh * C + c];
        }
        #pragma unroll
        for (int off = 32; off; off >>= 1) {
            ps += __shfl_xor(ps, off);
            pd += __shfl_xor(pd, off);
        }
        if (lane == 0) { aS[wave * 4 + hh] = ps; aD[wave * 4 + hh] = pd; }
    }
}

// ---------------- edge passes (atomic max / sum on [N,4] buffers) ----------------
__global__ void edge_max_k(const int* __restrict__ srcA, const int* __restrict__ dstA,
                           const float* __restrict__ aS, const float* __restrict__ aD,
                           float* __restrict__ m) {
    int e = blockIdx.x * blockDim.x + threadIdx.x;
    if (e >= ETOT) return;
    int s, d;
    if (e < NE) { s = srcA[e]; d = dstA[e]; } else { s = d = e - NE; }
    float4 vs = *(const float4*)&aS[s * 4];
    float4 vd = *(const float4*)&aD[d * 4];
    atomicMaxF(&m[d * 4 + 0], leaky02(vs.x + vd.x));
    atomicMaxF(&m[d * 4 + 1], leaky02(vs.y + vd.y));
    atomicMaxF(&m[d * 4 + 2], leaky02(vs.z + vd.z));
    atomicMaxF(&m[d * 4 + 3], leaky02(vs.w + vd.w));
}

__global__ void edge_sum_k(const int* __restrict__ srcA, const int* __restrict__ dstA,
                           const float* __restrict__ aS, const float* __restrict__ aD,
                           const float* __restrict__ m, float* __restrict__ ssum) {
    int e = blockIdx.x * blockDim.x + threadIdx.x;
    if (e >= ETOT) return;
    int s, d;
    if (e < NE) { s = srcA[e]; d = dstA[e]; } else { s = d = e - NE; }
    float4 vs = *(const float4*)&aS[s * 4];
    float4 vd = *(const float4*)&aD[d * 4];
    float4 mm = *(const float4*)&m[d * 4];
    atomicAdd(&ssum[d * 4 + 0], __expf(leaky02(vs.x + vd.x) - mm.x));
    atomicAdd(&ssum[d * 4 + 1], __expf(leaky02(vs.y + vd.y) - mm.y));
    atomicAdd(&ssum[d * 4 + 2], __expf(leaky02(vs.z + vd.z) - mm.z));
    atomicAdd(&ssum[d * 4 + 3], __expf(leaky02(vs.w + vd.w) - mm.w));
}

// ---------------- CSR build ----------------
__global__ void hist_k(const int* __restrict__ dstA, int* __restrict__ counts) {
    int e = blockIdx.x * blockDim.x + threadIdx.x;
    if (e >= ETOT) return;
    int d = (e < NE) ? dstA[e] : e - NE;
    atomicAdd(&counts[d], 1);
}

__global__ void scan_k(const int* __restrict__ counts, int* __restrict__ offsets,
                       int* __restrict__ cursor) {
    __shared__ int sums[1024];
    const int CH = 49;                 // 1024*49 = 50176 >= NN
    int t = threadIdx.x;
    int base = t * CH;
    int loc[CH];
    int run = 0;
    #pragma unroll
    for (int i = 0; i < CH; ++i) {
        int idx = base + i;
        int v = (idx < NN) ? counts[idx] : 0;
        loc[i] = run;
        run += v;
    }
    sums[t] = run;
    __syncthreads();
    for (int dd = 1; dd < 1024; dd <<= 1) {
        int v = (t >= dd) ? sums[t - dd] : 0;
        __syncthreads();
        sums[t] += v;
        __syncthreads();
    }
    int excl = sums[t] - run;
    #pragma unroll
    for (int i = 0; i < CH; ++i) {
        int idx = base + i;
        if (idx < NN) {
            int o = excl + loc[i];
            offsets[idx] = o;
            cursor[idx] = o;
        }
    }
    if (t == 1023) offsets[NN] = sums[1023];
}

__global__ void fill_k(const int* __restrict__ srcA, const int* __restrict__ dstA,
                       int* __restrict__ cursor, int* __restrict__ csr_src) {
    int e = blockIdx.x * blockDim.x + threadIdx.x;
    if (e >= ETOT) return;
    int s, d;
    if (e < NE) { s = srcA[e]; d = dstA[e]; } else { s = d = e - NE; }
    int pos = atomicAdd(&cursor[d], 1);
    csr_src[pos] = s;
}

// ---------------- layer-1 aggregation: CSR gather + bias + BN + ELU fused -------
__global__ void gather1_k(const int* __restrict__ csr_src, const int* __restrict__ offsets,
                          const float* __restrict__ aS, const float* __restrict__ aD,
                          const float* __restrict__ mb, const float* __restrict__ sb,
                          const float* __restrict__ h1, const float* __restrict__ b1,
                          const float* __restrict__ bg, const float* __restrict__ bb,
                          float* __restrict__ x2) {
    int d = (blockIdx.x << 2) + (threadIdx.x >> 6);
    if (d >= NN) return;
    int lane = threadIdx.x & 63;
    int c = lane * 2;
    int head = c >> 5;
    float adh = aD[d * 4 + head];
    float mh  = mb[d * 4 + head];
    float inv = 1.f / (sb[d * 4 + head] + 1e-16f);
    int o0 = offsets[d], o1 = offsets[d + 1];
    float acc0 = 0.f, acc1 = 0.f;
    for (int o = o0; o < o1; ++o) {
        int s = csr_src[o];
        float ash = aS[s * 4 + head];
        float w = __expf(leaky02(ash + adh) - mh) * inv;
        float2 hv = *(const float2*)&h1[(long)s * 128 + c];
        acc0 += w * hv.x;
        acc1 += w * hv.y;
    }
    float v0 = (acc0 + b1[c]) * BN_K * bg[c] + bb[c];
    float v1 = (acc1 + b1[c + 1]) * BN_K * bg[c + 1] + bb[c + 1];
    v0 = v0 > 0.f ? v0 : __expf(v0) - 1.f;
    v1 = v1 > 0.f ? v1 : __expf(v1) - 1.f;
    *(float2*)&x2[(long)d * 128 + c] = make_float2(v0, v1);
}

// ---------------- layer-2: per-source weight accumulation ----------------
__global__ void wacc_k(const int* __restrict__ srcA, const int* __restrict__ dstA,
                       const float* __restrict__ aS, const float* __restrict__ aD,
                       const float* __restrict__ mb, const float* __restrict__ sb,
                       float* __restrict__ Wacc) {
    int e = blockIdx.x * blockDim.x + threadIdx.x;
    if (e >= ETOT) return;
    int s, d;
    if (e < NE) { s = srcA[e]; d = dstA[e]; } else { s = d = e - NE; }
    float4 vs = *(const float4*)&aS[s * 4];
    float4 vd = *(const float4*)&aD[d * 4];
    float4 mm = *(const float4*)&mb[d * 4];
    float4 ss = *(const float4*)&sb[d * 4];
    const float scale = 0.25f / (float)NN;
    atomicAdd(&Wacc[s * 4 + 0], scale * __expf(leaky02(vs.x + vd.x) - mm.x) / (ss.x + 1e-16f));
    atomicAdd(&Wacc[s * 4 + 1], scale * __expf(leaky02(vs.y + vd.y) - mm.y) / (ss.y + 1e-16f));
    atomicAdd(&Wacc[s * 4 + 2], scale * __expf(leaky02(vs.z + vd.z) - mm.z) / (ss.z + 1e-16f));
    atomicAdd(&Wacc[s * 4 + 3], scale * __expf(leaky02(vs.w + vd.w) - mm.w) / (ss.w + 1e-16f));
}

// total[c] = sum_r Wacc[r] * h2[r*128+c], r in [0, 4*NN)
__global__ void gemv_k(const float* __restrict__ Wacc, const float* __restrict__ h2,
                       float* __restrict__ total) {
    int c = threadIdx.x;  // 128
    float acc = 0.f;
    for (int r = blockIdx.x; r < 4 * NN; r += gridDim.x)
        acc += Wacc[r] * h2[(long)r * 128 + c];
    atomicAdd(&total[c], acc);
}

__global__ void final2_k(const float* __restrict__ total, const float* __restrict__ b2,
                         const float* __restrict__ W, const float* __restrict__ ob,
                         float* __restrict__ out) {
    __shared__ float xm[128];
    int c = threadIdx.x;
    xm[c] = total[c] + b2[c];
    __syncthreads();
    float acc = ob[c];
    for (int k = 0; k < 128; ++k) acc += xm[k] * W[k * 128 + c];
    out[c] = acc > 0.f ? acc : 0.f;
}

extern "C" void kernel_launch(void* const* d_in, const int* in_sizes, int n_in,
                              void* d_out, int out_size, void* d_ws, size_t ws_size,
                              hipStream_t stream) {
    const float* x0  = (const float*)d_in[0];
    const int*   ei  = (const int*)d_in[1];
    const float* pW  = (const float*)d_in[2];
    const float* pb  = (const float*)d_in[3];
    const float* W1  = (const float*)d_in[4];
    const float* as1 = (const float*)d_in[5];
    const float* ad1 = (const float*)d_in[6];
    const float* b1  = (const float*)d_in[7];
    const float* bg  = (const float*)d_in[8];
    const float* bb  = (const float*)d_in[9];
    const float* W2  = (const float*)d_in[10];
    const float* as2 = (const float*)d_in[11];
    const float* ad2 = (const float*)d_in[12];
    const float* b2  = (const float*)d_in[13];
    const float* oW  = (const float*)d_in[14];
    const float* ob  = (const float*)d_in[15];
    float* out = (float*)d_out;

    float* ws = (float*)d_ws;
    float* x1    = ws; ws += 6400000;      // [N,128] proj output
    float* h1    = ws; ws += 6400000;      // [N,128] layer-1 features
    float* x2    = ws; ws += 6400000;      // [N,128] layer-1 output (post BN/ELU)
    float* h2    = ws; ws += 25600000;     // [N,512] layer-2 features
    float* aS    = ws; ws += 200000;
    float* aD    = ws; ws += 200000;
    float* mb    = ws; ws += 200000;
    float* sb    = ws; ws += 200000;
    float* Wacc  = ws; ws += 200000;
    float* total = ws; ws += 128;
    int* counts  = (int*)ws; ws += 50000;
    int* offsets = (int*)ws; ws += 50004;
    int* cursor  = (int*)ws; ws += 50000;
    int* csr_src = (int*)ws; ws += 1650000;

    const int* srcA = ei;
    const int* dstA = ei + NE;

    hipMemsetAsync(counts, 0, (size_t)50000 * 4, stream);
    hipMemsetAsync(mb, 0xFF, (size_t)200000 * 4, stream);
    hipMemsetAsync(sb, 0, (size_t)200000 * 4, stream);
    hipMemsetAsync(Wacc, 0, (size_t)200000 * 4, stream);
    hipMemsetAsync(total, 0, (size_t)128 * 4, stream);

    dim3 blk(256);
    const int egrid = (ETOT + 255) / 256;

    // CSR build (independent of features)
    hist_k<<<egrid, blk, 0, stream>>>(dstA, counts);
    scan_k<<<1, 1024, 0, stream>>>(counts, offsets, cursor);
    fill_k<<<egrid, blk, 0, stream>>>(srcA, dstA, cursor, csr_src);

    // layer 0/1
    gemm_k128<1><<<dim3(782, 2), blk, 0, stream>>>(x0, pW, pb, x1, NN, 128);
    gemm_k128<0><<<dim3(782, 2), blk, 0, stream>>>(x1, W1, nullptr, h1, NN, 128);
    att_reduce<32><<<12500, blk, 0, stream>>>(h1, as1, ad1, aS, aD);
    edge_max_k<<<egrid, blk, 0, stream>>>(srcA, dstA, aS, aD, mb);
    edge_sum_k<<<egrid, blk, 0, stream>>>(srcA, dstA, aS, aD, mb, sb);
    gather1_k<<<12500, blk, 0, stream>>>(csr_src, offsets, aS, aD, mb, sb, h1, b1, bg, bb, x2);

    // layer 2
    gemm_k128<0><<<dim3(782, 8), blk, 0, stream>>>(x2, W2, nullptr, h2, NN, 512);
    att_reduce<128><<<12500, blk, 0, stream>>>(h2, as2, ad2, aS, aD);
    hipMemsetAsync(mb, 0xFF, (size_t)200000 * 4, stream);
    hipMemsetAsync(sb, 0, (size_t)200000 * 4, stream);
    edge_max_k<<<egrid, blk, 0, stream>>>(srcA, dstA, aS, aD, mb);
    edge_sum_k<<<egrid, blk, 0, stream>>>(srcA, dstA, aS, aD, mb, sb);
    wacc_k<<<egrid, blk, 0, stream>>>(srcA, dstA, aS, aD, mb, sb, Wacc);
    gemv_k<<<512, 128, 0, stream>>>(Wacc, h2, total);
    final2_k<<<1, 128, 0, stream>>>(total, b2, oW, ob, out);
}

// Round 4
// 1226.782 us; speedup vs baseline: 3.5286x; 1.9591x over previous
//
#include <hip/hip_runtime.h>
#include <hip/hip_bf16.h>

#define NN 50000
#define NE 1600000
#define ETOT (NE + NN)   // 1,650,000 (self-loops appended)
#define BN_K 0.9999950000374997f
#define NEG_SENT -1e30f

__device__ __forceinline__ float leaky02(float x) { return x > 0.f ? x : 0.2f * x; }

// ---------------- GEMM: C[M,N] = act(A[M,128] @ B[128,N] + bias) ----------------
template<int ACT>
__global__ void gemm_k128(const float* __restrict__ A, const float* __restrict__ B,
                          const float* __restrict__ bias, float* __restrict__ C,
                          int M, int N) {
    __shared__ float As[64][68];
    __shared__ float Bs[64][68];
    const int tid = threadIdx.x;
    const int ty = tid >> 4, tx = tid & 15;
    const int row0 = blockIdx.x * 64;
    const int col0 = blockIdx.y * 64;
    float acc[4][4] = {};
    for (int kk = 0; kk < 128; kk += 64) {
        #pragma unroll
        for (int t = 0; t < 4; ++t) {
            int f = tid + t * 256;
            int r = f >> 4;
            int c4 = (f & 15) << 2;
            int gr = row0 + r;
            float4 v = make_float4(0.f, 0.f, 0.f, 0.f);
            if (gr < M) v = *(const float4*)&A[(long)gr * 128 + kk + c4];
            As[r][c4] = v.x; As[r][c4 + 1] = v.y; As[r][c4 + 2] = v.z; As[r][c4 + 3] = v.w;
        }
        #pragma unroll
        for (int t = 0; t < 4; ++t) {
            int f = tid + t * 256;
            int r = f >> 4;
            int c4 = (f & 15) << 2;
            float4 v = *(const float4*)&B[(long)(kk + r) * N + col0 + c4];
            Bs[r][c4] = v.x; Bs[r][c4 + 1] = v.y; Bs[r][c4 + 2] = v.z; Bs[r][c4 + 3] = v.w;
        }
        __syncthreads();
        #pragma unroll
        for (int k = 0; k < 64; ++k) {
            float a0 = As[ty * 4 + 0][k];
            float a1 = As[ty * 4 + 1][k];
            float a2 = As[ty * 4 + 2][k];
            float a3 = As[ty * 4 + 3][k];
            float4 b = *(const float4*)&Bs[k][tx * 4];
            acc[0][0] += a0 * b.x; acc[0][1] += a0 * b.y; acc[0][2] += a0 * b.z; acc[0][3] += a0 * b.w;
            acc[1][0] += a1 * b.x; acc[1][1] += a1 * b.y; acc[1][2] += a1 * b.z; acc[1][3] += a1 * b.w;
            acc[2][0] += a2 * b.x; acc[2][1] += a2 * b.y; acc[2][2] += a2 * b.z; acc[2][3] += a2 * b.w;
            acc[3][0] += a3 * b.x; acc[3][1] += a3 * b.y; acc[3][2] += a3 * b.z; acc[3][3] += a3 * b.w;
        }
        __syncthreads();
    }
    #pragma unroll
    for (int i = 0; i < 4; ++i) {
        int gr = row0 + ty * 4 + i;
        if (gr >= M) continue;
        #pragma unroll
        for (int j = 0; j < 4; ++j) {
            int gc = col0 + tx * 4 + j;
            float v = acc[i][j] + (bias ? bias[gc] : 0.f);
            if (ACT == 1) v = v > 0.f ? v : 0.f;
            C[(long)gr * N + gc] = v;
        }
    }
}

// ---------------- attention coefficients ----------------
template<int C>
__global__ void att_reduce(const float* __restrict__ h, const float* __restrict__ attS,
                           const float* __restrict__ attD, float* __restrict__ aS,
                           float* __restrict__ aD) {
    int wave = (int)((blockIdx.x * (long)blockDim.x + threadIdx.x) >> 6);
    int lane = threadIdx.x & 63;
    if (wave >= NN) return;
    const float* row = h + (long)wave * (4 * C);
    #pragma unroll
    for (int hh = 0; hh < 4; ++hh) {
        float ps = 0.f, pd = 0.f;
        for (int c = lane; c < C; c += 64) {
            float v = row[hh * C + c];
            ps += v * attS[hh * C + c];
            pd += v * attD[hh * C + c];
        }
        #pragma unroll
        for (int off = 32; off; off >>= 1) {
            ps += __shfl_xor(ps, off);
            pd += __shfl_xor(pd, off);
        }
        if (lane == 0) { aS[wave * 4 + hh] = ps; aD[wave * 4 + hh] = pd; }
    }
}

// ---------------- CSR build (generic: key = grouping index) ----------------
__global__ void hist_k(const int* __restrict__ keyA, int* __restrict__ counts) {
    int e = blockIdx.x * blockDim.x + threadIdx.x;
    if (e >= ETOT) return;
    int d = (e < NE) ? keyA[e] : e - NE;
    atomicAdd(&counts[d], 1);
}

__global__ void scan_k(const int* __restrict__ counts, int* __restrict__ offsets,
                       int* __restrict__ cursor) {
    __shared__ int sums[1024];
    const int CH = 49;                 // 1024*49 = 50176 >= NN
    int t = threadIdx.x;
    int base = t * CH;
    int loc[CH];
    int run = 0;
    #pragma unroll
    for (int i = 0; i < CH; ++i) {
        int idx = base + i;
        int v = (idx < NN) ? counts[idx] : 0;
        loc[i] = run;
        run += v;
    }
    sums[t] = run;
    __syncthreads();
    for (int dd = 1; dd < 1024; dd <<= 1) {
        int v = (t >= dd) ? sums[t - dd] : 0;
        __syncthreads();
        sums[t] += v;
        __syncthreads();
    }
    int excl = sums[t] - run;
    #pragma unroll
    for (int i = 0; i < CH; ++i) {
        int idx = base + i;
        if (idx < NN) {
            int o = excl + loc[i];
            offsets[idx] = o;
            cursor[idx] = o;
        }
    }
    if (t == 1023) offsets[NN] = sums[1023];
}

__global__ void fill_k(const int* __restrict__ keyA, const int* __restrict__ valA,
                       int* __restrict__ cursor, int* __restrict__ csr_val) {
    int e = blockIdx.x * blockDim.x + threadIdx.x;
    if (e >= ETOT) return;
    int k, v;
    if (e < NE) { k = keyA[e]; v = valA[e]; } else { k = v = e - NE; }
    int pos = atomicAdd(&cursor[k], 1);
    csr_val[pos] = v;
}

// online (max, sum-of-exp) combine
__device__ __forceinline__ void osm_upd(float& m, float& s, float e) {
    float nm = fmaxf(m, e);
    s = s * __expf(m - nm) + __expf(e - nm);
    m = nm;
}
__device__ __forceinline__ void osm_red(float& m, float& s) {
    #pragma unroll
    for (int off = 32; off; off >>= 1) {
        float om = __shfl_xor(m, off);
        float os = __shfl_xor(s, off);
        float nm = fmaxf(m, om);
        s = s * __expf(m - nm) + os * __expf(om - nm);
        m = nm;
    }
}

// ---------------- layer-1: fused softmax + CSR gather + bias + BN + ELU ---------
__global__ void gather1_k(const int* __restrict__ csr_src, const int* __restrict__ offsets,
                          const float* __restrict__ aS, const float* __restrict__ aD,
                          const float* __restrict__ h1, const float* __restrict__ b1,
                          const float* __restrict__ bg, const float* __restrict__ bb,
                          float* __restrict__ x2) {
    int d = (blockIdx.x << 2) + (threadIdx.x >> 6);
    if (d >= NN) return;
    int lane = threadIdx.x & 63;
    float4 ad4 = *(const float4*)&aD[d * 4];
    int o0 = offsets[d], o1 = offsets[d + 1];
    float m0 = NEG_SENT, m1 = NEG_SENT, m2 = NEG_SENT, m3 = NEG_SENT;
    float s0 = 0.f, s1 = 0.f, s2 = 0.f, s3 = 0.f;
    for (int o = o0 + lane; o < o1; o += 64) {
        int s = csr_src[o];
        float4 as4 = *(const float4*)&aS[s * 4];
        osm_upd(m0, s0, leaky02(as4.x + ad4.x));
        osm_upd(m1, s1, leaky02(as4.y + ad4.y));
        osm_upd(m2, s2, leaky02(as4.z + ad4.z));
        osm_upd(m3, s3, leaky02(as4.w + ad4.w));
    }
    osm_red(m0, s0); osm_red(m1, s1); osm_red(m2, s2); osm_red(m3, s3);

    int c = lane * 2;
    int head = c >> 5;
    float mh  = (head == 0) ? m0 : (head == 1) ? m1 : (head == 2) ? m2 : m3;
    float sh  = (head == 0) ? s0 : (head == 1) ? s1 : (head == 2) ? s2 : s3;
    float adh = (head == 0) ? ad4.x : (head == 1) ? ad4.y : (head == 2) ? ad4.z : ad4.w;
    float inv = 1.f / (sh + 1e-16f);
    float acc0 = 0.f, acc1 = 0.f;
    for (int o = o0; o < o1; ++o) {
        int s = csr_src[o];
        float ash = aS[s * 4 + head];
        float w = __expf(leaky02(ash + adh) - mh) * inv;
        float2 hv = *(const float2*)&h1[(long)s * 128 + c];
        acc0 += w * hv.x;
        acc1 += w * hv.y;
    }
    float v0 = (acc0 + b1[c]) * BN_K * bg[c] + bb[c];
    float v1 = (acc1 + b1[c + 1]) * BN_K * bg[c + 1] + bb[c + 1];
    v0 = v0 > 0.f ? v0 : __expf(v0) - 1.f;
    v1 = v1 > 0.f ? v1 : __expf(v1) - 1.f;
    *(float2*)&x2[(long)d * 128 + c] = make_float2(v0, v1);
}

// ---------------- layer-2: per-dst max/sum via CSR (no atomics) ----------------
__global__ void dmaxsum_k(const int* __restrict__ csr_src, const int* __restrict__ offsets,
                          const float* __restrict__ aS, const float* __restrict__ aD,
                          float* __restrict__ mb, float* __restrict__ sb) {
    int d = (blockIdx.x << 2) + (threadIdx.x >> 6);
    if (d >= NN) return;
    int lane = threadIdx.x & 63;
    float4 ad4 = *(const float4*)&aD[d * 4];
    int o0 = offsets[d], o1 = offsets[d + 1];
    float m0 = NEG_SENT, m1 = NEG_SENT, m2 = NEG_SENT, m3 = NEG_SENT;
    float s0 = 0.f, s1 = 0.f, s2 = 0.f, s3 = 0.f;
    for (int o = o0 + lane; o < o1; o += 64) {
        int s = csr_src[o];
        float4 as4 = *(const float4*)&aS[s * 4];
        osm_upd(m0, s0, leaky02(as4.x + ad4.x));
        osm_upd(m1, s1, leaky02(as4.y + ad4.y));
        osm_upd(m2, s2, leaky02(as4.z + ad4.z));
        osm_upd(m3, s3, leaky02(as4.w + ad4.w));
    }
    osm_red(m0, s0); osm_red(m1, s1); osm_red(m2, s2); osm_red(m3, s3);
    if (lane == 0) {
        *(float4*)&mb[d * 4] = make_float4(m0, m1, m2, m3);
        *(float4*)&sb[d * 4] = make_float4(s0, s1, s2, s3);
    }
}

// ---------------- layer-2: per-src weight via src-CSR (no atomics) -------------
__global__ void waccg_k(const int* __restrict__ csr_dst, const int* __restrict__ offsetsS,
                        const float* __restrict__ aS, const float* __restrict__ aD,
                        const float* __restrict__ mb, const float* __restrict__ sb,
                        float* __restrict__ Wacc) {
    int s = (blockIdx.x << 2) + (threadIdx.x >> 6);
    if (s >= NN) return;
    int lane = threadIdx.x & 63;
    float4 as4 = *(const float4*)&aS[s * 4];
    int o0 = offsetsS[s], o1 = offsetsS[s + 1];
    float a0 = 0.f, a1 = 0.f, a2 = 0.f, a3 = 0.f;
    for (int o = o0 + lane; o < o1; o += 64) {
        int d = csr_dst[o];
        float4 ad4 = *(const float4*)&aD[d * 4];
        float4 mm  = *(const float4*)&mb[d * 4];
        float4 ss  = *(const float4*)&sb[d * 4];
        a0 += __expf(leaky02(as4.x + ad4.x) - mm.x) / (ss.x + 1e-16f);
        a1 += __expf(leaky02(as4.y + ad4.y) - mm.y) / (ss.y + 1e-16f);
        a2 += __expf(leaky02(as4.z + ad4.z) - mm.z) / (ss.z + 1e-16f);
        a3 += __expf(leaky02(as4.w + ad4.w) - mm.w) / (ss.w + 1e-16f);
    }
    #pragma unroll
    for (int off = 32; off; off >>= 1) {
        a0 += __shfl_xor(a0, off);
        a1 += __shfl_xor(a1, off);
        a2 += __shfl_xor(a2, off);
        a3 += __shfl_xor(a3, off);
    }
    if (lane == 0) {
        const float scale = 0.25f / (float)NN;
        *(float4*)&Wacc[s * 4] = make_float4(scale * a0, scale * a1, scale * a2, scale * a3);
    }
}

// total[c] = sum_r Wacc[r] * h2[r*128+c], r in [0, 4*NN)
__global__ void gemv_k(const float* __restrict__ Wacc, const float* __restrict__ h2,
                       float* __restrict__ total) {
    int c = threadIdx.x;  // 128
    float acc = 0.f;
    for (int r = blockIdx.x; r < 4 * NN; r += gridDim.x)
        acc += Wacc[r] * h2[(long)r * 128 + c];
    atomicAdd(&total[c], acc);
}

__global__ void final2_k(const float* __restrict__ total, const float* __restrict__ b2,
                         const float* __restrict__ W, const float* __restrict__ ob,
                         float* __restrict__ out) {
    __shared__ float xm[128];
    int c = threadIdx.x;
    xm[c] = total[c] + b2[c];
    __syncthreads();
    float acc = ob[c];
    for (int k = 0; k < 128; ++k) acc += xm[k] * W[k * 128 + c];
    out[c] = acc > 0.f ? acc : 0.f;
}

extern "C" void kernel_launch(void* const* d_in, const int* in_sizes, int n_in,
                              void* d_out, int out_size, void* d_ws, size_t ws_size,
                              hipStream_t stream) {
    const float* x0  = (const float*)d_in[0];
    const int*   ei  = (const int*)d_in[1];
    const float* pW  = (const float*)d_in[2];
    const float* pb  = (const float*)d_in[3];
    const float* W1  = (const float*)d_in[4];
    const float* as1 = (const float*)d_in[5];
    const float* ad1 = (const float*)d_in[6];
    const float* b1  = (const float*)d_in[7];
    const float* bg  = (const float*)d_in[8];
    const float* bb  = (const float*)d_in[9];
    const float* W2  = (const float*)d_in[10];
    const float* as2 = (const float*)d_in[11];
    const float* ad2 = (const float*)d_in[12];
    const float* b2  = (const float*)d_in[13];
    const float* oW  = (const float*)d_in[14];
    const float* ob  = (const float*)d_in[15];
    float* out = (float*)d_out;

    float* ws = (float*)d_ws;
    float* x1    = ws; ws += 6400000;      // [N,128]
    float* h1    = ws; ws += 6400000;      // [N,128]
    float* x2    = ws; ws += 6400000;      // [N,128]
    float* h2    = ws; ws += 25600000;     // [N,512]
    float* aS    = ws; ws += 200000;
    float* aD    = ws; ws += 200000;
    float* mb    = ws; ws += 200000;
    float* sb    = ws; ws += 200000;
    float* Wacc  = ws; ws += 200000;
    float* total = ws; ws += 128;
    int* counts_d = (int*)ws; ws += 50000;
    int* offs_d   = (int*)ws; ws += 50004;
    int* cursor_d = (int*)ws; ws += 50000;
    int* csr_src  = (int*)ws; ws += 1650000;
    int* counts_s = (int*)ws; ws += 50000;
    int* offs_s   = (int*)ws; ws += 50004;
    int* cursor_s = (int*)ws; ws += 50000;
    int* csr_dst  = (int*)ws; ws += 1650000;

    const int* srcA = ei;
    const int* dstA = ei + NE;

    hipMemsetAsync(counts_d, 0, (size_t)50000 * 4, stream);
    hipMemsetAsync(counts_s, 0, (size_t)50000 * 4, stream);
    hipMemsetAsync(total, 0, (size_t)128 * 4, stream);

    dim3 blk(256);
    const int egrid = (ETOT + 255) / 256;

    // CSR builds (independent of features)
    hist_k<<<egrid, blk, 0, stream>>>(dstA, counts_d);
    scan_k<<<1, 1024, 0, stream>>>(counts_d, offs_d, cursor_d);
    fill_k<<<egrid, blk, 0, stream>>>(dstA, srcA, cursor_d, csr_src);
    hist_k<<<egrid, blk, 0, stream>>>(srcA, counts_s);
    scan_k<<<1, 1024, 0, stream>>>(counts_s, offs_s, cursor_s);
    fill_k<<<egrid, blk, 0, stream>>>(srcA, dstA, cursor_s, csr_dst);

    // layer 0/1
    gemm_k128<1><<<dim3(782, 2), blk, 0, stream>>>(x0, pW, pb, x1, NN, 128);
    gemm_k128<0><<<dim3(782, 2), blk, 0, stream>>>(x1, W1, nullptr, h1, NN, 128);
    att_reduce<32><<<12500, blk, 0, stream>>>(h1, as1, ad1, aS, aD);
    gather1_k<<<12500, blk, 0, stream>>>(csr_src, offs_d, aS, aD, h1, b1, bg, bb, x2);

    // layer 2
    gemm_k128<0><<<dim3(782, 8), blk, 0, stream>>>(x2, W2, nullptr, h2, NN, 512);
    att_reduce<128><<<12500, blk, 0, stream>>>(h2, as2, ad2, aS, aD);
    dmaxsum_k<<<12500, blk, 0, stream>>>(csr_src, offs_d, aS, aD, mb, sb);
    waccg_k<<<12500, blk, 0, stream>>>(csr_dst, offs_s, aS, aD, mb, sb, Wacc);
    gemv_k<<<512, 128, 0, stream>>>(Wacc, h2, total);
    final2_k<<<1, 128, 0, stream>>>(total, b2, oW, ob, out);
}

// Round 5
// 988.719 us; speedup vs baseline: 4.3782x; 1.2408x over previous
//
#include <hip/hip_runtime.h>
#include <hip/hip_bf16.h>

#define NN 50000
#define NE 1600000
#define ETOT (NE + NN)   // 1,650,000 (self-loops appended)
#define BN_K 0.9999950000374997f
#define NEG_SENT -1e30f

__device__ __forceinline__ float leaky02(float x) { return x > 0.f ? x : 0.2f * x; }

// ---------------- GEMM: C[M,N] = act(A[M,128] @ B[128,N] + bias) ----------------
template<int ACT>
__global__ void gemm_k128(const float* __restrict__ A, const float* __restrict__ B,
                          const float* __restrict__ bias, float* __restrict__ C,
                          int M, int N) {
    __shared__ float As[64][68];
    __shared__ float Bs[64][68];
    const int tid = threadIdx.x;
    const int ty = tid >> 4, tx = tid & 15;
    const int row0 = blockIdx.x * 64;
    const int col0 = blockIdx.y * 64;
    float acc[4][4] = {};
    for (int kk = 0; kk < 128; kk += 64) {
        #pragma unroll
        for (int t = 0; t < 4; ++t) {
            int f = tid + t * 256;
            int r = f >> 4;
            int c4 = (f & 15) << 2;
            int gr = row0 + r;
            float4 v = make_float4(0.f, 0.f, 0.f, 0.f);
            if (gr < M) v = *(const float4*)&A[(long)gr * 128 + kk + c4];
            As[r][c4] = v.x; As[r][c4 + 1] = v.y; As[r][c4 + 2] = v.z; As[r][c4 + 3] = v.w;
        }
        #pragma unroll
        for (int t = 0; t < 4; ++t) {
            int f = tid + t * 256;
            int r = f >> 4;
            int c4 = (f & 15) << 2;
            float4 v = *(const float4*)&B[(long)(kk + r) * N + col0 + c4];
            Bs[r][c4] = v.x; Bs[r][c4 + 1] = v.y; Bs[r][c4 + 2] = v.z; Bs[r][c4 + 3] = v.w;
        }
        __syncthreads();
        #pragma unroll
        for (int k = 0; k < 64; ++k) {
            float a0 = As[ty * 4 + 0][k];
            float a1 = As[ty * 4 + 1][k];
            float a2 = As[ty * 4 + 2][k];
            float a3 = As[ty * 4 + 3][k];
            float4 b = *(const float4*)&Bs[k][tx * 4];
            acc[0][0] += a0 * b.x; acc[0][1] += a0 * b.y; acc[0][2] += a0 * b.z; acc[0][3] += a0 * b.w;
            acc[1][0] += a1 * b.x; acc[1][1] += a1 * b.y; acc[1][2] += a1 * b.z; acc[1][3] += a1 * b.w;
            acc[2][0] += a2 * b.x; acc[2][1] += a2 * b.y; acc[2][2] += a2 * b.z; acc[2][3] += a2 * b.w;
            acc[3][0] += a3 * b.x; acc[3][1] += a3 * b.y; acc[3][2] += a3 * b.z; acc[3][3] += a3 * b.w;
        }
        __syncthreads();
    }
    #pragma unroll
    for (int i = 0; i < 4; ++i) {
        int gr = row0 + ty * 4 + i;
        if (gr >= M) continue;
        #pragma unroll
        for (int j = 0; j < 4; ++j) {
            int gc = col0 + tx * 4 + j;
            float v = acc[i][j] + (bias ? bias[gc] : 0.f);
            if (ACT == 1) v = v > 0.f ? v : 0.f;
            C[(long)gr * N + gc] = v;
        }
    }
}

// ---------------- attention coefficients (layer 1, C=32) ----------------
__global__ void att_reduce1(const float* __restrict__ h, const float* __restrict__ attS,
                            const float* __restrict__ attD, float* __restrict__ aS,
                            float* __restrict__ aD) {
    int wave = (int)((blockIdx.x * (long)blockDim.x + threadIdx.x) >> 6);
    int lane = threadIdx.x & 63;
    if (wave >= NN) return;
    const float* row = h + (long)wave * 128;
    #pragma unroll
    for (int hh = 0; hh < 4; ++hh) {
        float ps = 0.f, pd = 0.f;
        for (int c = lane; c < 32; c += 64) {
            float v = row[hh * 32 + c];
            ps += v * attS[hh * 32 + c];
            pd += v * attD[hh * 32 + c];
        }
        #pragma unroll
        for (int off = 32; off; off >>= 1) {
            ps += __shfl_xor(ps, off);
            pd += __shfl_xor(pd, off);
        }
        if (lane == 0) { aS[wave * 4 + hh] = ps; aD[wave * 4 + hh] = pd; }
    }
}

// ---------------- CSR build (both keyings in one pass) ----------------
__global__ void hist2_k(const int* __restrict__ srcA, const int* __restrict__ dstA,
                        int* __restrict__ counts_d, int* __restrict__ counts_s) {
    int e = blockIdx.x * blockDim.x + threadIdx.x;
    if (e >= ETOT) return;
    int s, d;
    if (e < NE) { s = srcA[e]; d = dstA[e]; } else { s = d = e - NE; }
    atomicAdd(&counts_d[d], 1);
    atomicAdd(&counts_s[s], 1);
}

__global__ void scan2_k(const int* __restrict__ counts_d, int* __restrict__ offs_d,
                        int* __restrict__ cur_d,
                        const int* __restrict__ counts_s, int* __restrict__ offs_s,
                        int* __restrict__ cur_s) {
    const int* counts = blockIdx.x ? counts_s : counts_d;
    int* offsets = blockIdx.x ? offs_s : offs_d;
    int* cursor  = blockIdx.x ? cur_s : cur_d;
    __shared__ int sums[1024];
    const int CH = 49;                 // 1024*49 = 50176 >= NN
    int t = threadIdx.x;
    int base = t * CH;
    int loc[CH];
    int run = 0;
    #pragma unroll
    for (int i = 0; i < CH; ++i) {
        int idx = base + i;
        int v = (idx < NN) ? counts[idx] : 0;
        loc[i] = run;
        run += v;
    }
    sums[t] = run;
    __syncthreads();
    for (int dd = 1; dd < 1024; dd <<= 1) {
        int v = (t >= dd) ? sums[t - dd] : 0;
        __syncthreads();
        sums[t] += v;
        __syncthreads();
    }
    int excl = sums[t] - run;
    #pragma unroll
    for (int i = 0; i < CH; ++i) {
        int idx = base + i;
        if (idx < NN) {
            int o = excl + loc[i];
            offsets[idx] = o;
            cursor[idx] = o;
        }
    }
    if (t == 1023) offsets[NN] = sums[1023];
}

__global__ void fill2_k(const int* __restrict__ srcA, const int* __restrict__ dstA,
                        int* __restrict__ cur_d, int* __restrict__ cur_s,
                        int* __restrict__ csr_src, int* __restrict__ csr_dst) {
    int e = blockIdx.x * blockDim.x + threadIdx.x;
    if (e >= ETOT) return;
    int s, d;
    if (e < NE) { s = srcA[e]; d = dstA[e]; } else { s = d = e - NE; }
    int p = atomicAdd(&cur_d[d], 1);
    csr_src[p] = s;
    int q = atomicAdd(&cur_s[s], 1);
    csr_dst[q] = d;
}

// online (max, sum-of-exp) combine
__device__ __forceinline__ void osm_upd(float& m, float& s, float e) {
    float nm = fmaxf(m, e);
    s = s * __expf(m - nm) + __expf(e - nm);
    m = nm;
}
__device__ __forceinline__ void osm_red(float& m, float& s) {
    #pragma unroll
    for (int off = 32; off; off >>= 1) {
        float om = __shfl_xor(m, off);
        float os = __shfl_xor(s, off);
        float nm = fmaxf(m, om);
        s = s * __expf(m - nm) + os * __expf(om - nm);
        m = nm;
    }
}

// ---------------- layer-1: fused softmax + CSR gather + bias + BN + ELU ---------
// LDS-staged per-edge weights: 1 lane computes all 4 head-weights for 1 edge,
// then whole wave consumes via broadcast reads (16x fewer exps than naive).
__global__ void gather1_k(const int* __restrict__ csr_src, const int* __restrict__ offsets,
                          const float* __restrict__ aS, const float* __restrict__ aD,
                          const float* __restrict__ h1, const float* __restrict__ b1,
                          const float* __restrict__ bg, const float* __restrict__ bb,
                          float* __restrict__ x2) {
    __shared__ float4 wst[4][64];
    __shared__ int    sst[4][64];
    int wv = threadIdx.x >> 6;
    int d = (blockIdx.x << 2) + wv;
    if (d >= NN) return;
    int lane = threadIdx.x & 63;
    float4 ad4 = *(const float4*)&aD[d * 4];
    int o0 = offsets[d], o1 = offsets[d + 1];
    // phase A: online softmax stats
    float m0 = NEG_SENT, m1 = NEG_SENT, m2 = NEG_SENT, m3 = NEG_SENT;
    float s0 = 0.f, s1 = 0.f, s2 = 0.f, s3 = 0.f;
    for (int o = o0 + lane; o < o1; o += 64) {
        int s = csr_src[o];
        float4 as4 = *(const float4*)&aS[s * 4];
        osm_upd(m0, s0, leaky02(as4.x + ad4.x));
        osm_upd(m1, s1, leaky02(as4.y + ad4.y));
        osm_upd(m2, s2, leaky02(as4.z + ad4.z));
        osm_upd(m3, s3, leaky02(as4.w + ad4.w));
    }
    osm_red(m0, s0); osm_red(m1, s1); osm_red(m2, s2); osm_red(m3, s3);
    float i0 = 1.f / (s0 + 1e-16f), i1 = 1.f / (s1 + 1e-16f);
    float i2 = 1.f / (s2 + 1e-16f), i3 = 1.f / (s3 + 1e-16f);

    // phase B: chunked weighted gather
    int c = lane * 2;
    int head = c >> 5;
    float acc0 = 0.f, acc1 = 0.f;
    for (int base = o0; base < o1; base += 64) {
        int e = base + lane;
        if (e < o1) {
            int s = csr_src[e];
            float4 as4 = *(const float4*)&aS[s * 4];
            float4 w;
            w.x = __expf(leaky02(as4.x + ad4.x) - m0) * i0;
            w.y = __expf(leaky02(as4.y + ad4.y) - m1) * i1;
            w.z = __expf(leaky02(as4.z + ad4.z) - m2) * i2;
            w.w = __expf(leaky02(as4.w + ad4.w) - m3) * i3;
            wst[wv][lane] = w;
            sst[wv][lane] = s;
        }
        __threadfence_block();   // wave-synchronous LDS: order write -> read
        int lim = min(64, o1 - base);
        for (int i = 0; i < lim; ++i) {
            float w = ((const float*)&wst[wv][i])[head];
            int s = sst[wv][i];
            float2 hv = *(const float2*)&h1[(long)s * 128 + c];
            acc0 += w * hv.x;
            acc1 += w * hv.y;
        }
    }
    float v0 = (acc0 + b1[c]) * BN_K * bg[c] + bb[c];
    float v1 = (acc1 + b1[c + 1]) * BN_K * bg[c + 1] + bb[c + 1];
    v0 = v0 > 0.f ? v0 : __expf(v0) - 1.f;
    v1 = v1 > 0.f ? v1 : __expf(v1) - 1.f;
    *(float2*)&x2[(long)d * 128 + c] = make_float2(v0, v1);
}

// ---------------- layer-2 algebraic folding ----------------
// va_{s,d}[h,k] = sum_c W2[k, h*128+c] * att_{src,dst}2[h,c]
__global__ void fold_k(const float* __restrict__ W2, const float* __restrict__ as2,
                       const float* __restrict__ ad2, float* __restrict__ va_s,
                       float* __restrict__ va_d) {
    int h = blockIdx.x;        // 4
    int k = threadIdx.x;       // 128
    const float* wrow = W2 + (long)k * 512 + h * 128;
    float accs = 0.f, accd = 0.f;
    for (int ci = 0; ci < 128; ++ci) {
        float w = wrow[ci];
        accs += w * as2[h * 128 + ci];
        accd += w * ad2[h * 128 + ci];
    }
    va_s[h * 128 + k] = accs;
    va_d[h * 128 + k] = accd;
}

// aS2[n,h] = x2[n,:] . va_s[h,:]   (same for aD2)
__global__ void att2_k(const float* __restrict__ x2, const float* __restrict__ va_s,
                       const float* __restrict__ va_d, float* __restrict__ aS,
                       float* __restrict__ aD) {
    int n = (blockIdx.x << 2) + (threadIdx.x >> 6);
    if (n >= NN) return;
    int lane = threadIdx.x & 63;
    float2 x = *(const float2*)&x2[(long)n * 128 + lane * 2];
    float r[8];
    #pragma unroll
    for (int h = 0; h < 4; ++h) {
        float2 vs = *(const float2*)&va_s[h * 128 + lane * 2];
        float2 vd = *(const float2*)&va_d[h * 128 + lane * 2];
        r[h]     = x.x * vs.x + x.y * vs.y;
        r[4 + h] = x.x * vd.x + x.y * vd.y;
    }
    #pragma unroll
    for (int off = 32; off; off >>= 1) {
        #pragma unroll
        for (int j = 0; j < 8; ++j) r[j] += __shfl_xor(r[j], off);
    }
    if (lane == 0) {
        *(float4*)&aS[n * 4] = make_float4(r[0], r[1], r[2], r[3]);
        *(float4*)&aD[n * 4] = make_float4(r[4], r[5], r[6], r[7]);
    }
}

// ---------------- layer-2: per-dst max/sum via CSR (no atomics) ----------------
__global__ void dmaxsum_k(const int* __restrict__ csr_src, const int* __restrict__ offsets,
                          const float* __restrict__ aS, const float* __restrict__ aD,
                          float* __restrict__ mb, float* __restrict__ sb) {
    int d = (blockIdx.x << 2) + (threadIdx.x >> 6);
    if (d >= NN) return;
    int lane = threadIdx.x & 63;
    float4 ad4 = *(const float4*)&aD[d * 4];
    int o0 = offsets[d], o1 = offsets[d + 1];
    float m0 = NEG_SENT, m1 = NEG_SENT, m2 = NEG_SENT, m3 = NEG_SENT;
    float s0 = 0.f, s1 = 0.f, s2 = 0.f, s3 = 0.f;
    for (int o = o0 + lane; o < o1; o += 64) {
        int s = csr_src[o];
        float4 as4 = *(const float4*)&aS[s * 4];
        osm_upd(m0, s0, leaky02(as4.x + ad4.x));
        osm_upd(m1, s1, leaky02(as4.y + ad4.y));
        osm_upd(m2, s2, leaky02(as4.z + ad4.z));
        osm_upd(m3, s3, leaky02(as4.w + ad4.w));
    }
    osm_red(m0, s0); osm_red(m1, s1); osm_red(m2, s2); osm_red(m3, s3);
    if (lane == 0) {
        *(float4*)&mb[d * 4] = make_float4(m0, m1, m2, m3);
        *(float4*)&sb[d * 4] = make_float4(s0, s1, s2, s3);
    }
}

// ---------------- layer-2: per-src weight via src-CSR (no atomics) -------------
__global__ void waccg_k(const int* __restrict__ csr_dst, const int* __restrict__ offsetsS,
                        const float* __restrict__ aS, const float* __restrict__ aD,
                        const float* __restrict__ mb, const float* __restrict__ sb,
                        float* __restrict__ Wacc) {
    int s = (blockIdx.x << 2) + (threadIdx.x >> 6);
    if (s >= NN) return;
    int lane = threadIdx.x & 63;
    float4 as4 = *(const float4*)&aS[s * 4];
    int o0 = offsetsS[s], o1 = offsetsS[s + 1];
    float a0 = 0.f, a1 = 0.f, a2 = 0.f, a3 = 0.f;
    for (int o = o0 + lane; o < o1; o += 64) {
        int d = csr_dst[o];
        float4 ad4 = *(const float4*)&aD[d * 4];
        float4 mm  = *(const float4*)&mb[d * 4];
        float4 ss  = *(const float4*)&sb[d * 4];
        a0 += __expf(leaky02(as4.x + ad4.x) - mm.x) / (ss.x + 1e-16f);
        a1 += __expf(leaky02(as4.y + ad4.y) - mm.y) / (ss.y + 1e-16f);
        a2 += __expf(leaky02(as4.z + ad4.z) - mm.z) / (ss.z + 1e-16f);
        a3 += __expf(leaky02(as4.w + ad4.w) - mm.w) / (ss.w + 1e-16f);
    }
    #pragma unroll
    for (int off = 32; off; off >>= 1) {
        a0 += __shfl_xor(a0, off);
        a1 += __shfl_xor(a1, off);
        a2 += __shfl_xor(a2, off);
        a3 += __shfl_xor(a3, off);
    }
    if (lane == 0) {
        const float scale = 0.25f / (float)NN;
        *(float4*)&Wacc[s * 4] = make_float4(scale * a0, scale * a1, scale * a2, scale * a3);
    }
}

// y[h,k] = sum_r Wacc[r,h] * x2[r,k]
__global__ void yacc_k(const float* __restrict__ Wacc, const float* __restrict__ x2,
                       float* __restrict__ y) {
    int k = threadIdx.x;  // 128
    float a0 = 0.f, a1 = 0.f, a2 = 0.f, a3 = 0.f;
    for (int r = blockIdx.x; r < NN; r += gridDim.x) {
        float4 w = *(const float4*)&Wacc[r * 4];
        float x = x2[(long)r * 128 + k];
        a0 += w.x * x; a1 += w.y * x; a2 += w.z * x; a3 += w.w * x;
    }
    atomicAdd(&y[0 * 128 + k], a0);
    atomicAdd(&y[1 * 128 + k], a1);
    atomicAdd(&y[2 * 128 + k], a2);
    atomicAdd(&y[3 * 128 + k], a3);
}

// total[c] = sum_h y[h,:] . W2[:, h*128+c]; then + b2, @ out_W, relu
__global__ void final2_k(const float* __restrict__ y, const float* __restrict__ W2,
                         const float* __restrict__ b2, const float* __restrict__ oW,
                         const float* __restrict__ ob, float* __restrict__ out) {
    __shared__ float xm[128];
    int c = threadIdx.x;
    float t = b2[c];
    #pragma unroll
    for (int h = 0; h < 4; ++h) {
        const float* yh = y + h * 128;
        for (int k = 0; k < 128; ++k) t += yh[k] * W2[(long)k * 512 + h * 128 + c];
    }
    xm[c] = t;
    __syncthreads();
    float acc = ob[c];
    for (int k = 0; k < 128; ++k) acc += xm[k] * oW[k * 128 + c];
    out[c] = acc > 0.f ? acc : 0.f;
}

extern "C" void kernel_launch(void* const* d_in, const int* in_sizes, int n_in,
                              void* d_out, int out_size, void* d_ws, size_t ws_size,
                              hipStream_t stream) {
    const float* x0  = (const float*)d_in[0];
    const int*   ei  = (const int*)d_in[1];
    const float* pW  = (const float*)d_in[2];
    const float* pb  = (const float*)d_in[3];
    const float* W1  = (const float*)d_in[4];
    const float* as1 = (const float*)d_in[5];
    const float* ad1 = (const float*)d_in[6];
    const float* b1  = (const float*)d_in[7];
    const float* bg  = (const float*)d_in[8];
    const float* bb  = (const float*)d_in[9];
    const float* W2  = (const float*)d_in[10];
    const float* as2 = (const float*)d_in[11];
    const float* ad2 = (const float*)d_in[12];
    const float* b2  = (const float*)d_in[13];
    const float* oW  = (const float*)d_in[14];
    const float* ob  = (const float*)d_in[15];
    float* out = (float*)d_out;

    float* ws = (float*)d_ws;
    float* x1    = ws; ws += 6400000;      // [N,128]
    float* h1    = ws; ws += 6400000;      // [N,128]
    float* x2    = ws; ws += 6400000;      // [N,128]
    float* aS    = ws; ws += 200000;
    float* aD    = ws; ws += 200000;
    float* mb    = ws; ws += 200000;
    float* sb    = ws; ws += 200000;
    float* Wacc  = ws; ws += 200000;
    float* va_s  = ws; ws += 512;
    float* va_d  = ws; ws += 512;
    float* y     = ws; ws += 512;
    int* counts_d = (int*)ws; ws += 50000;
    int* offs_d   = (int*)ws; ws += 50004;
    int* cursor_d = (int*)ws; ws += 50000;
    int* csr_src  = (int*)ws; ws += 1650000;
    int* counts_s = (int*)ws; ws += 50000;
    int* offs_s   = (int*)ws; ws += 50004;
    int* cursor_s = (int*)ws; ws += 50000;
    int* csr_dst  = (int*)ws; ws += 1650000;

    const int* srcA = ei;
    const int* dstA = ei + NE;

    hipMemsetAsync(counts_d, 0, (size_t)50000 * 4, stream);
    hipMemsetAsync(counts_s, 0, (size_t)50000 * 4, stream);
    hipMemsetAsync(y, 0, (size_t)512 * 4, stream);

    dim3 blk(256);
    const int egrid = (ETOT + 255) / 256;

    // CSR builds (both keyings, fused passes)
    hist2_k<<<egrid, blk, 0, stream>>>(srcA, dstA, counts_d, counts_s);
    scan2_k<<<2, 1024, 0, stream>>>(counts_d, offs_d, cursor_d, counts_s, offs_s, cursor_s);
    fill2_k<<<egrid, blk, 0, stream>>>(srcA, dstA, cursor_d, cursor_s, csr_src, csr_dst);

    // layer 0/1
    gemm_k128<1><<<dim3(782, 2), blk, 0, stream>>>(x0, pW, pb, x1, NN, 128);
    gemm_k128<0><<<dim3(782, 2), blk, 0, stream>>>(x1, W1, nullptr, h1, NN, 128);
    att_reduce1<<<12500, blk, 0, stream>>>(h1, as1, ad1, aS, aD);
    gather1_k<<<12500, blk, 0, stream>>>(csr_src, offs_d, aS, aD, h1, b1, bg, bb, x2);

    // layer 2 (h2 never materialized)
    fold_k<<<4, 128, 0, stream>>>(W2, as2, ad2, va_s, va_d);
    att2_k<<<12500, blk, 0, stream>>>(x2, va_s, va_d, aS, aD);
    dmaxsum_k<<<12500, blk, 0, stream>>>(csr_src, offs_d, aS, aD, mb, sb);
    waccg_k<<<12500, blk, 0, stream>>>(csr_dst, offs_s, aS, aD, mb, sb, Wacc);
    yacc_k<<<256, 128, 0, stream>>>(Wacc, x2, y);
    final2_k<<<1, 128, 0, stream>>>(y, W2, b2, oW, ob, out);
}

// Round 6
// 567.347 us; speedup vs baseline: 7.6298x; 1.7427x over previous
//
#include <hip/hip_runtime.h>
#include <hip/hip_bf16.h>

#define NN 50000
#define NE 1600000
#define ETOT (NE + NN)   // 1,650,000 (self-loops appended)
#define BN_K 0.9999950000374997f
#define NEG_SENT -1e30f

#define SHIFT 7
#define NPB 128                        // nodes per bucket
#define NB ((NN + NPB - 1) >> SHIFT)   // 391 buckets
#define CHUNK 4096
#define PGRID ((ETOT + CHUNK - 1) / CHUNK)   // 403

__device__ __forceinline__ float leaky02(float x) { return x > 0.f ? x : 0.2f * x; }

// ---------------- GEMM: C[M,N] = act(A[M,128] @ B[128,N] + bias) ----------------
template<int ACT>
__global__ void gemm_k128(const float* __restrict__ A, const float* __restrict__ B,
                          const float* __restrict__ bias, float* __restrict__ C,
                          int M, int N) {
    __shared__ float As[64][68];
    __shared__ float Bs[64][68];
    const int tid = threadIdx.x;
    const int ty = tid >> 4, tx = tid & 15;
    const int row0 = blockIdx.x * 64;
    const int col0 = blockIdx.y * 64;
    float acc[4][4] = {};
    for (int kk = 0; kk < 128; kk += 64) {
        #pragma unroll
        for (int t = 0; t < 4; ++t) {
            int f = tid + t * 256;
            int r = f >> 4;
            int c4 = (f & 15) << 2;
            int gr = row0 + r;
            float4 v = make_float4(0.f, 0.f, 0.f, 0.f);
            if (gr < M) v = *(const float4*)&A[(long)gr * 128 + kk + c4];
            As[r][c4] = v.x; As[r][c4 + 1] = v.y; As[r][c4 + 2] = v.z; As[r][c4 + 3] = v.w;
        }
        #pragma unroll
        for (int t = 0; t < 4; ++t) {
            int f = tid + t * 256;
            int r = f >> 4;
            int c4 = (f & 15) << 2;
            float4 v = *(const float4*)&B[(long)(kk + r) * N + col0 + c4];
            Bs[r][c4] = v.x; Bs[r][c4 + 1] = v.y; Bs[r][c4 + 2] = v.z; Bs[r][c4 + 3] = v.w;
        }
        __syncthreads();
        #pragma unroll
        for (int k = 0; k < 64; ++k) {
            float a0 = As[ty * 4 + 0][k];
            float a1 = As[ty * 4 + 1][k];
            float a2 = As[ty * 4 + 2][k];
            float a3 = As[ty * 4 + 3][k];
            float4 b = *(const float4*)&Bs[k][tx * 4];
            acc[0][0] += a0 * b.x; acc[0][1] += a0 * b.y; acc[0][2] += a0 * b.z; acc[0][3] += a0 * b.w;
            acc[1][0] += a1 * b.x; acc[1][1] += a1 * b.y; acc[1][2] += a1 * b.z; acc[1][3] += a1 * b.w;
            acc[2][0] += a2 * b.x; acc[2][1] += a2 * b.y; acc[2][2] += a2 * b.z; acc[2][3] += a2 * b.w;
            acc[3][0] += a3 * b.x; acc[3][1] += a3 * b.y; acc[3][2] += a3 * b.z; acc[3][3] += a3 * b.w;
        }
        __syncthreads();
    }
    #pragma unroll
    for (int i = 0; i < 4; ++i) {
        int gr = row0 + ty * 4 + i;
        if (gr >= M) continue;
        #pragma unroll
        for (int j = 0; j < 4; ++j) {
            int gc = col0 + tx * 4 + j;
            float v = acc[i][j] + (bias ? bias[gc] : 0.f);
            if (ACT == 1) v = v > 0.f ? v : 0.f;
            C[(long)gr * N + gc] = v;
        }
    }
}

// ---------------- attention coefficients (layer 1, C=32) ----------------
__global__ void att_reduce1(const float* __restrict__ h, const float* __restrict__ attS,
                            const float* __restrict__ attD, float* __restrict__ aS,
                            float* __restrict__ aD) {
    int wave = (int)((blockIdx.x * (long)blockDim.x + threadIdx.x) >> 6);
    int lane = threadIdx.x & 63;
    if (wave >= NN) return;
    const float* row = h + (long)wave * 128;
    #pragma unroll
    for (int hh = 0; hh < 4; ++hh) {
        float ps = 0.f, pd = 0.f;
        for (int c = lane; c < 32; c += 64) {
            float v = row[hh * 32 + c];
            ps += v * attS[hh * 32 + c];
            pd += v * attD[hh * 32 + c];
        }
        #pragma unroll
        for (int off = 32; off; off >>= 1) {
            ps += __shfl_xor(ps, off);
            pd += __shfl_xor(pd, off);
        }
        if (lane == 0) { aS[wave * 4 + hh] = ps; aD[wave * 4 + hh] = pd; }
    }
}

// ================= CSR build: two-level counting sort =================
// P0: global bucket histograms (both keyings), LDS-staged
__global__ void bhist_k(const int* __restrict__ srcA, const int* __restrict__ dstA,
                        int* __restrict__ bcnt_d, int* __restrict__ bcnt_s) {
    __shared__ int hd[NB], hs[NB];
    for (int i = threadIdx.x; i < NB; i += 256) { hd[i] = 0; hs[i] = 0; }
    __syncthreads();
    int e0 = blockIdx.x * CHUNK;
    int e1 = min(e0 + CHUNK, ETOT);
    for (int e = e0 + threadIdx.x; e < e1; e += 256) {
        int s, d;
        if (e < NE) { s = srcA[e]; d = dstA[e]; } else { s = d = e - NE; }
        atomicAdd(&hd[d >> SHIFT], 1);
        atomicAdd(&hs[s >> SHIFT], 1);
    }
    __syncthreads();
    for (int i = threadIdx.x; i < NB; i += 256) {
        if (hd[i]) atomicAdd(&bcnt_d[i], hd[i]);
        if (hs[i]) atomicAdd(&bcnt_s[i], hs[i]);
    }
}

// P0.5: scan bucket counts -> bucket offsets + cursors (block 0: d, block 1: s)
__global__ void bscan_k(const int* __restrict__ bcnt_d, int* __restrict__ boffs_d,
                        int* __restrict__ bcur_d, int* __restrict__ noffs_d,
                        const int* __restrict__ bcnt_s, int* __restrict__ boffs_s,
                        int* __restrict__ bcur_s, int* __restrict__ noffs_s) {
    const int* bcnt = blockIdx.x ? bcnt_s : bcnt_d;
    int* boffs = blockIdx.x ? boffs_s : boffs_d;
    int* bcur  = blockIdx.x ? bcur_s : bcur_d;
    int* noffs = blockIdx.x ? noffs_s : noffs_d;
    __shared__ int v[512];
    int t = threadIdx.x;
    int x = (t < NB) ? bcnt[t] : 0;
    v[t] = x;
    __syncthreads();
    for (int dd = 1; dd < 512; dd <<= 1) {
        int y = (t >= dd) ? v[t - dd] : 0;
        __syncthreads();
        v[t] += y;
        __syncthreads();
    }
    if (t < NB) { int o = v[t] - x; boffs[t] = o; bcur[t] = o; }
    if (t == NB - 1) boffs[NB] = v[t];
    if (t == 0) noffs[NN] = ETOT;
}

// P1: partition edges into bucket-major pair arrays (pair = {key_node, payload})
__global__ void part_k(const int* __restrict__ srcA, const int* __restrict__ dstA,
                       int* __restrict__ bcur_d, int* __restrict__ bcur_s,
                       int2* __restrict__ pr_d, int2* __restrict__ pr_s) {
    __shared__ int hd[NB], hs[NB], bd[NB], bs[NB];
    for (int i = threadIdx.x; i < NB; i += 256) { hd[i] = 0; hs[i] = 0; }
    __syncthreads();
    int e0 = blockIdx.x * CHUNK;
    int e1 = min(e0 + CHUNK, ETOT);
    for (int e = e0 + threadIdx.x; e < e1; e += 256) {
        int s, d;
        if (e < NE) { s = srcA[e]; d = dstA[e]; } else { s = d = e - NE; }
        atomicAdd(&hd[d >> SHIFT], 1);
        atomicAdd(&hs[s >> SHIFT], 1);
    }
    __syncthreads();
    for (int i = threadIdx.x; i < NB; i += 256) {
        if (hd[i]) { bd[i] = atomicAdd(&bcur_d[i], hd[i]); hd[i] = 0; }
        if (hs[i]) { bs[i] = atomicAdd(&bcur_s[i], hs[i]); hs[i] = 0; }
    }
    __syncthreads();
    for (int e = e0 + threadIdx.x; e < e1; e += 256) {
        int s, d;
        if (e < NE) { s = srcA[e]; d = dstA[e]; } else { s = d = e - NE; }
        int kd = d >> SHIFT;
        int idx = bd[kd] + atomicAdd(&hd[kd], 1);
        pr_d[idx] = make_int2(d, s);
        int ks = s >> SHIFT;
        int idx2 = bs[ks] + atomicAdd(&hs[ks], 1);
        pr_s[idx2] = make_int2(s, d);
    }
}

// P2: within-bucket fine sort -> node offsets + csr payload (one block per bucket)
__global__ void fine_k(const int2* __restrict__ pr, const int* __restrict__ boffs,
                       int* __restrict__ noffs, int* __restrict__ csr) {
    __shared__ int cnt[NPB], off[NPB];
    int bkt = blockIdx.x;
    int n0 = bkt << SHIFT;
    int base = boffs[bkt], end = boffs[bkt + 1];
    int t = threadIdx.x;
    if (t < NPB) cnt[t] = 0;
    __syncthreads();
    for (int i = base + t; i < end; i += 256)
        atomicAdd(&cnt[pr[i].x - n0], 1);
    __syncthreads();
    if (t < NPB) off[t] = cnt[t];
    __syncthreads();
    for (int dd = 1; dd < NPB; dd <<= 1) {
        int y = 0;
        if (t < NPB && t >= dd) y = off[t - dd];
        __syncthreads();
        if (t < NPB) off[t] += y;
        __syncthreads();
    }
    if (t < NPB) {
        int excl = off[t] - cnt[t];
        int n = n0 + t;
        if (n < NN) noffs[n] = base + excl;
        off[t] = excl;
        cnt[t] = 0;
    }
    __syncthreads();
    for (int i = base + t; i < end; i += 256) {
        int2 p = pr[i];
        int j = p.x - n0;
        int pos = base + off[j] + atomicAdd(&cnt[j], 1);
        csr[pos] = p.y;
    }
}

// online (max, sum-of-exp) combine
__device__ __forceinline__ void osm_upd(float& m, float& s, float e) {
    float nm = fmaxf(m, e);
    s = s * __expf(m - nm) + __expf(e - nm);
    m = nm;
}
__device__ __forceinline__ void osm_red(float& m, float& s) {
    #pragma unroll
    for (int off = 32; off; off >>= 1) {
        float om = __shfl_xor(m, off);
        float os = __shfl_xor(s, off);
        float nm = fmaxf(m, om);
        s = s * __expf(m - nm) + os * __expf(om - nm);
        m = nm;
    }
}

// ---------------- layer-1: fused softmax + CSR gather + bias + BN + ELU ---------
__global__ void gather1_k(const int* __restrict__ csr_src, const int* __restrict__ offsets,
                          const float* __restrict__ aS, const float* __restrict__ aD,
                          const float* __restrict__ h1, const float* __restrict__ b1,
                          const float* __restrict__ bg, const float* __restrict__ bb,
                          float* __restrict__ x2) {
    __shared__ float4 wst[4][64];
    __shared__ int    sst[4][64];
    int wv = threadIdx.x >> 6;
    int d = (blockIdx.x << 2) + wv;
    if (d >= NN) return;
    int lane = threadIdx.x & 63;
    float4 ad4 = *(const float4*)&aD[d * 4];
    int o0 = offsets[d], o1 = offsets[d + 1];
    float m0 = NEG_SENT, m1 = NEG_SENT, m2 = NEG_SENT, m3 = NEG_SENT;
    float s0 = 0.f, s1 = 0.f, s2 = 0.f, s3 = 0.f;
    for (int o = o0 + lane; o < o1; o += 64) {
        int s = csr_src[o];
        float4 as4 = *(const float4*)&aS[s * 4];
        osm_upd(m0, s0, leaky02(as4.x + ad4.x));
        osm_upd(m1, s1, leaky02(as4.y + ad4.y));
        osm_upd(m2, s2, leaky02(as4.z + ad4.z));
        osm_upd(m3, s3, leaky02(as4.w + ad4.w));
    }
    osm_red(m0, s0); osm_red(m1, s1); osm_red(m2, s2); osm_red(m3, s3);
    float i0 = 1.f / (s0 + 1e-16f), i1 = 1.f / (s1 + 1e-16f);
    float i2 = 1.f / (s2 + 1e-16f), i3 = 1.f / (s3 + 1e-16f);

    int c = lane * 2;
    int head = c >> 5;
    float acc0 = 0.f, acc1 = 0.f;
    for (int base = o0; base < o1; base += 64) {
        int e = base + lane;
        if (e < o1) {
            int s = csr_src[e];
            float4 as4 = *(const float4*)&aS[s * 4];
            float4 w;
            w.x = __expf(leaky02(as4.x + ad4.x) - m0) * i0;
            w.y = __expf(leaky02(as4.y + ad4.y) - m1) * i1;
            w.z = __expf(leaky02(as4.z + ad4.z) - m2) * i2;
            w.w = __expf(leaky02(as4.w + ad4.w) - m3) * i3;
            wst[wv][lane] = w;
            sst[wv][lane] = s;
        }
        __threadfence_block();
        int lim = min(64, o1 - base);
        for (int i = 0; i < lim; ++i) {
            float w = ((const float*)&wst[wv][i])[head];
            int s = sst[wv][i];
            float2 hv = *(const float2*)&h1[(long)s * 128 + c];
            acc0 += w * hv.x;
            acc1 += w * hv.y;
        }
    }
    float v0 = (acc0 + b1[c]) * BN_K * bg[c] + bb[c];
    float v1 = (acc1 + b1[c + 1]) * BN_K * bg[c + 1] + bb[c + 1];
    v0 = v0 > 0.f ? v0 : __expf(v0) - 1.f;
    v1 = v1 > 0.f ? v1 : __expf(v1) - 1.f;
    *(float2*)&x2[(long)d * 128 + c] = make_float2(v0, v1);
}

// ---------------- layer-2 algebraic folding ----------------
__global__ void fold_k(const float* __restrict__ W2, const float* __restrict__ as2,
                       const float* __restrict__ ad2, float* __restrict__ va_s,
                       float* __restrict__ va_d) {
    int h = blockIdx.x;        // 4
    int k = threadIdx.x;       // 128
    const float* wrow = W2 + (long)k * 512 + h * 128;
    float accs = 0.f, accd = 0.f;
    for (int ci = 0; ci < 128; ++ci) {
        float w = wrow[ci];
        accs += w * as2[h * 128 + ci];
        accd += w * ad2[h * 128 + ci];
    }
    va_s[h * 128 + k] = accs;
    va_d[h * 128 + k] = accd;
}

__global__ void att2_k(const float* __restrict__ x2, const float* __restrict__ va_s,
                       const float* __restrict__ va_d, float* __restrict__ aS,
                       float* __restrict__ aD) {
    int n = (blockIdx.x << 2) + (threadIdx.x >> 6);
    if (n >= NN) return;
    int lane = threadIdx.x & 63;
    float2 x = *(const float2*)&x2[(long)n * 128 + lane * 2];
    float r[8];
    #pragma unroll
    for (int h = 0; h < 4; ++h) {
        float2 vs = *(const float2*)&va_s[h * 128 + lane * 2];
        float2 vd = *(const float2*)&va_d[h * 128 + lane * 2];
        r[h]     = x.x * vs.x + x.y * vs.y;
        r[4 + h] = x.x * vd.x + x.y * vd.y;
    }
    #pragma unroll
    for (int off = 32; off; off >>= 1) {
        #pragma unroll
        for (int j = 0; j < 8; ++j) r[j] += __shfl_xor(r[j], off);
    }
    if (lane == 0) {
        *(float4*)&aS[n * 4] = make_float4(r[0], r[1], r[2], r[3]);
        *(float4*)&aD[n * 4] = make_float4(r[4], r[5], r[6], r[7]);
    }
}

// ---------------- layer-2: per-dst max/sum via CSR (no atomics) ----------------
__global__ void dmaxsum_k(const int* __restrict__ csr_src, const int* __restrict__ offsets,
                          const float* __restrict__ aS, const float* __restrict__ aD,
                          float* __restrict__ mb, float* __restrict__ sb) {
    int d = (blockIdx.x << 2) + (threadIdx.x >> 6);
    if (d >= NN) return;
    int lane = threadIdx.x & 63;
    float4 ad4 = *(const float4*)&aD[d * 4];
    int o0 = offsets[d], o1 = offsets[d + 1];
    float m0 = NEG_SENT, m1 = NEG_SENT, m2 = NEG_SENT, m3 = NEG_SENT;
    float s0 = 0.f, s1 = 0.f, s2 = 0.f, s3 = 0.f;
    for (int o = o0 + lane; o < o1; o += 64) {
        int s = csr_src[o];
        float4 as4 = *(const float4*)&aS[s * 4];
        osm_upd(m0, s0, leaky02(as4.x + ad4.x));
        osm_upd(m1, s1, leaky02(as4.y + ad4.y));
        osm_upd(m2, s2, leaky02(as4.z + ad4.z));
        osm_upd(m3, s3, leaky02(as4.w + ad4.w));
    }
    osm_red(m0, s0); osm_red(m1, s1); osm_red(m2, s2); osm_red(m3, s3);
    if (lane == 0) {
        *(float4*)&mb[d * 4] = make_float4(m0, m1, m2, m3);
        *(float4*)&sb[d * 4] = make_float4(s0, s1, s2, s3);
    }
}

// ---------------- layer-2: per-src weight via src-CSR (no atomics) -------------
__global__ void waccg_k(const int* __restrict__ csr_dst, const int* __restrict__ offsetsS,
                        const float* __restrict__ aS, const float* __restrict__ aD,
                        const float* __restrict__ mb, const float* __restrict__ sb,
                        float* __restrict__ Wacc) {
    int s = (blockIdx.x << 2) + (threadIdx.x >> 6);
    if (s >= NN) return;
    int lane = threadIdx.x & 63;
    float4 as4 = *(const float4*)&aS[s * 4];
    int o0 = offsetsS[s], o1 = offsetsS[s + 1];
    float a0 = 0.f, a1 = 0.f, a2 = 0.f, a3 = 0.f;
    for (int o = o0 + lane; o < o1; o += 64) {
        int d = csr_dst[o];
        float4 ad4 = *(const float4*)&aD[d * 4];
        float4 mm  = *(const float4*)&mb[d * 4];
        float4 ss  = *(const float4*)&sb[d * 4];
        a0 += __expf(leaky02(as4.x + ad4.x) - mm.x) / (ss.x + 1e-16f);
        a1 += __expf(leaky02(as4.y + ad4.y) - mm.y) / (ss.y + 1e-16f);
        a2 += __expf(leaky02(as4.z + ad4.z) - mm.z) / (ss.z + 1e-16f);
        a3 += __expf(leaky02(as4.w + ad4.w) - mm.w) / (ss.w + 1e-16f);
    }
    #pragma unroll
    for (int off = 32; off; off >>= 1) {
        a0 += __shfl_xor(a0, off);
        a1 += __shfl_xor(a1, off);
        a2 += __shfl_xor(a2, off);
        a3 += __shfl_xor(a3, off);
    }
    if (lane == 0) {
        const float scale = 0.25f / (float)NN;
        *(float4*)&Wacc[s * 4] = make_float4(scale * a0, scale * a1, scale * a2, scale * a3);
    }
}

// y[h,k] = sum_r Wacc[r,h] * x2[r,k]
__global__ void yacc_k(const float* __restrict__ Wacc, const float* __restrict__ x2,
                       float* __restrict__ y) {
    int k = threadIdx.x;  // 128
    float a0 = 0.f, a1 = 0.f, a2 = 0.f, a3 = 0.f;
    for (int r = blockIdx.x; r < NN; r += gridDim.x) {
        float4 w = *(const float4*)&Wacc[r * 4];
        float x = x2[(long)r * 128 + k];
        a0 += w.x * x; a1 += w.y * x; a2 += w.z * x; a3 += w.w * x;
    }
    atomicAdd(&y[0 * 128 + k], a0);
    atomicAdd(&y[1 * 128 + k], a1);
    atomicAdd(&y[2 * 128 + k], a2);
    atomicAdd(&y[3 * 128 + k], a3);
}

__global__ void final2_k(const float* __restrict__ y, const float* __restrict__ W2,
                         const float* __restrict__ b2, const float* __restrict__ oW,
                         const float* __restrict__ ob, float* __restrict__ out) {
    __shared__ float xm[128];
    int c = threadIdx.x;
    float t = b2[c];
    #pragma unroll
    for (int h = 0; h < 4; ++h) {
        const float* yh = y + h * 128;
        for (int k = 0; k < 128; ++k) t += yh[k] * W2[(long)k * 512 + h * 128 + c];
    }
    xm[c] = t;
    __syncthreads();
    float acc = ob[c];
    for (int k = 0; k < 128; ++k) acc += xm[k] * oW[k * 128 + c];
    out[c] = acc > 0.f ? acc : 0.f;
}

extern "C" void kernel_launch(void* const* d_in, const int* in_sizes, int n_in,
                              void* d_out, int out_size, void* d_ws, size_t ws_size,
                              hipStream_t stream) {
    const float* x0  = (const float*)d_in[0];
    const int*   ei  = (const int*)d_in[1];
    const float* pW  = (const float*)d_in[2];
    const float* pb  = (const float*)d_in[3];
    const float* W1  = (const float*)d_in[4];
    const float* as1 = (const float*)d_in[5];
    const float* ad1 = (const float*)d_in[6];
    const float* b1  = (const float*)d_in[7];
    const float* bg  = (const float*)d_in[8];
    const float* bb  = (const float*)d_in[9];
    const float* W2  = (const float*)d_in[10];
    const float* as2 = (const float*)d_in[11];
    const float* ad2 = (const float*)d_in[12];
    const float* b2  = (const float*)d_in[13];
    const float* oW  = (const float*)d_in[14];
    const float* ob  = (const float*)d_in[15];
    float* out = (float*)d_out;

    float* ws = (float*)d_ws;
    float* x1    = ws; ws += 6400000;      // [N,128]
    float* h1    = ws; ws += 6400000;      // [N,128]
    float* x2    = ws; ws += 6400000;      // [N,128]
    float* aS    = ws; ws += 200000;
    float* aD    = ws; ws += 200000;
    float* mb    = ws; ws += 200000;
    float* sb    = ws; ws += 200000;
    float* Wacc  = ws; ws += 200000;
    float* va_s  = ws; ws += 512;
    float* va_d  = ws; ws += 512;
    float* y     = ws; ws += 512;
    int* bcnt_d  = (int*)ws; ws += NB;
    int* boffs_d = (int*)ws; ws += NB + 1;
    int* bcur_d  = (int*)ws; ws += NB;
    int* bcnt_s  = (int*)ws; ws += NB;
    int* boffs_s = (int*)ws; ws += NB + 1;
    int* bcur_s  = (int*)ws; ws += NB;
    int* offs_d  = (int*)ws; ws += NN + 1;
    int* offs_s  = (int*)ws; ws += NN + 1;
    int* csr_src = (int*)ws; ws += ETOT;
    int* csr_dst = (int*)ws; ws += ETOT;
    int2* pr_d   = (int2*)ws; ws += 2 * ETOT;
    int2* pr_s   = (int2*)ws; ws += 2 * ETOT;

    const int* srcA = ei;
    const int* dstA = ei + NE;

    hipMemsetAsync(bcnt_d, 0, (size_t)NB * 4, stream);
    hipMemsetAsync(bcnt_s, 0, (size_t)NB * 4, stream);
    hipMemsetAsync(y, 0, (size_t)512 * 4, stream);

    dim3 blk(256);

    // CSR builds: two-level counting sort, both keyings
    bhist_k<<<PGRID, blk, 0, stream>>>(srcA, dstA, bcnt_d, bcnt_s);
    bscan_k<<<2, 512, 0, stream>>>(bcnt_d, boffs_d, bcur_d, offs_d,
                                   bcnt_s, boffs_s, bcur_s, offs_s);
    part_k<<<PGRID, blk, 0, stream>>>(srcA, dstA, bcur_d, bcur_s, pr_d, pr_s);
    fine_k<<<NB, blk, 0, stream>>>(pr_d, boffs_d, offs_d, csr_src);
    fine_k<<<NB, blk, 0, stream>>>(pr_s, boffs_s, offs_s, csr_dst);

    // layer 0/1
    gemm_k128<1><<<dim3(782, 2), blk, 0, stream>>>(x0, pW, pb, x1, NN, 128);
    gemm_k128<0><<<dim3(782, 2), blk, 0, stream>>>(x1, W1, nullptr, h1, NN, 128);
    att_reduce1<<<12500, blk, 0, stream>>>(h1, as1, ad1, aS, aD);
    gather1_k<<<12500, blk, 0, stream>>>(csr_src, offs_d, aS, aD, h1, b1, bg, bb, x2);

    // layer 2 (h2 never materialized)
    fold_k<<<4, 128, 0, stream>>>(W2, as2, ad2, va_s, va_d);
    att2_k<<<12500, blk, 0, stream>>>(x2, va_s, va_d, aS, aD);
    dmaxsum_k<<<12500, blk, 0, stream>>>(csr_src, offs_d, aS, aD, mb, sb);
    waccg_k<<<12500, blk, 0, stream>>>(csr_dst, offs_s, aS, aD, mb, sb, Wacc);
    yacc_k<<<256, 128, 0, stream>>>(Wacc, x2, y);
    final2_k<<<1, 128, 0, stream>>>(y, W2, b2, oW, ob, out);
}

// Round 7
// 474.117 us; speedup vs baseline: 9.1302x; 1.1966x over previous
//
#include <hip/hip_runtime.h>
#include <hip/hip_bf16.h>

#define NN 50000
#define NE 1600000
#define ETOT (NE + NN)   // 1,650,000 (self-loops appended)
#define BN_K 0.9999950000374997f
#define NEG_SENT -1e30f

#define SHIFT 7
#define NPB 128                        // nodes per bucket
#define NB ((NN + NPB - 1) >> SHIFT)   // 391 buckets
#define CHUNK 4096
#define PGRID ((ETOT + CHUNK - 1) / CHUNK)   // 403

__device__ __forceinline__ float leaky02(float x) { return x > 0.f ? x : 0.2f * x; }

// manual bf16 RNE pack/unpack (avoids header quirks)
__device__ __forceinline__ unsigned short f2bf(float f) {
    unsigned int u = __float_as_uint(f);
    u += 0x7FFFu + ((u >> 16) & 1u);
    return (unsigned short)(u >> 16);
}

// ---------------- GEMM: C[M,N] = act(A[M,128] @ B[128,N] + bias) ----------------
template<int ACT>
__global__ void gemm_k128(const float* __restrict__ A, const float* __restrict__ B,
                          const float* __restrict__ bias, float* __restrict__ C,
                          int M, int N) {
    __shared__ float As[64][68];
    __shared__ float Bs[64][68];
    const int tid = threadIdx.x;
    const int ty = tid >> 4, tx = tid & 15;
    const int row0 = blockIdx.x * 64;
    const int col0 = blockIdx.y * 64;
    float acc[4][4] = {};
    for (int kk = 0; kk < 128; kk += 64) {
        #pragma unroll
        for (int t = 0; t < 4; ++t) {
            int f = tid + t * 256;
            int r = f >> 4;
            int c4 = (f & 15) << 2;
            int gr = row0 + r;
            float4 v = make_float4(0.f, 0.f, 0.f, 0.f);
            if (gr < M) v = *(const float4*)&A[(long)gr * 128 + kk + c4];
            As[r][c4] = v.x; As[r][c4 + 1] = v.y; As[r][c4 + 2] = v.z; As[r][c4 + 3] = v.w;
        }
        #pragma unroll
        for (int t = 0; t < 4; ++t) {
            int f = tid + t * 256;
            int r = f >> 4;
            int c4 = (f & 15) << 2;
            float4 v = *(const float4*)&B[(long)(kk + r) * N + col0 + c4];
            Bs[r][c4] = v.x; Bs[r][c4 + 1] = v.y; Bs[r][c4 + 2] = v.z; Bs[r][c4 + 3] = v.w;
        }
        __syncthreads();
        #pragma unroll
        for (int k = 0; k < 64; ++k) {
            float a0 = As[ty * 4 + 0][k];
            float a1 = As[ty * 4 + 1][k];
            float a2 = As[ty * 4 + 2][k];
            float a3 = As[ty * 4 + 3][k];
            float4 b = *(const float4*)&Bs[k][tx * 4];
            acc[0][0] += a0 * b.x; acc[0][1] += a0 * b.y; acc[0][2] += a0 * b.z; acc[0][3] += a0 * b.w;
            acc[1][0] += a1 * b.x; acc[1][1] += a1 * b.y; acc[1][2] += a1 * b.z; acc[1][3] += a1 * b.w;
            acc[2][0] += a2 * b.x; acc[2][1] += a2 * b.y; acc[2][2] += a2 * b.z; acc[2][3] += a2 * b.w;
            acc[3][0] += a3 * b.x; acc[3][1] += a3 * b.y; acc[3][2] += a3 * b.z; acc[3][3] += a3 * b.w;
        }
        __syncthreads();
    }
    #pragma unroll
    for (int i = 0; i < 4; ++i) {
        int gr = row0 + ty * 4 + i;
        if (gr >= M) continue;
        #pragma unroll
        for (int j = 0; j < 4; ++j) {
            int gc = col0 + tx * 4 + j;
            float v = acc[i][j] + (bias ? bias[gc] : 0.f);
            if (ACT == 1) v = v > 0.f ? v : 0.f;
            C[(long)gr * N + gc] = v;
        }
    }
}

// ---- GEMM2: h1 = x1 @ W1, fused epilogue: bf16 h1b + aS1/aD1 attention dots ----
__global__ void gemm2_k(const float* __restrict__ A, const float* __restrict__ B,
                        const float* __restrict__ attS, const float* __restrict__ attD,
                        unsigned short* __restrict__ h1b, float* __restrict__ aS,
                        float* __restrict__ aD) {
    __shared__ float As[64][68];
    __shared__ float Bs[64][68];
    const int tid = threadIdx.x;
    const int ty = tid >> 4, tx = tid & 15;
    const int row0 = blockIdx.x * 64;
    const int col0 = blockIdx.y * 64;
    float acc[4][4] = {};
    for (int kk = 0; kk < 128; kk += 64) {
        #pragma unroll
        for (int t = 0; t < 4; ++t) {
            int f = tid + t * 256;
            int r = f >> 4;
            int c4 = (f & 15) << 2;
            int gr = row0 + r;
            float4 v = make_float4(0.f, 0.f, 0.f, 0.f);
            if (gr < NN) v = *(const float4*)&A[(long)gr * 128 + kk + c4];
            As[r][c4] = v.x; As[r][c4 + 1] = v.y; As[r][c4 + 2] = v.z; As[r][c4 + 3] = v.w;
        }
        #pragma unroll
        for (int t = 0; t < 4; ++t) {
            int f = tid + t * 256;
            int r = f >> 4;
            int c4 = (f & 15) << 2;
            float4 v = *(const float4*)&B[(long)(kk + r) * 128 + col0 + c4];
            Bs[r][c4] = v.x; Bs[r][c4 + 1] = v.y; Bs[r][c4 + 2] = v.z; Bs[r][c4 + 3] = v.w;
        }
        __syncthreads();
        #pragma unroll
        for (int k = 0; k < 64; ++k) {
            float a0 = As[ty * 4 + 0][k];
            float a1 = As[ty * 4 + 1][k];
            float a2 = As[ty * 4 + 2][k];
            float a3 = As[ty * 4 + 3][k];
            float4 b = *(const float4*)&Bs[k][tx * 4];
            acc[0][0] += a0 * b.x; acc[0][1] += a0 * b.y; acc[0][2] += a0 * b.z; acc[0][3] += a0 * b.w;
            acc[1][0] += a1 * b.x; acc[1][1] += a1 * b.y; acc[1][2] += a1 * b.z; acc[1][3] += a1 * b.w;
            acc[2][0] += a2 * b.x; acc[2][1] += a2 * b.y; acc[2][2] += a2 * b.z; acc[2][3] += a2 * b.w;
            acc[3][0] += a3 * b.x; acc[3][1] += a3 * b.y; acc[3][2] += a3 * b.z; acc[3][3] += a3 * b.w;
        }
        __syncthreads();
    }
    // epilogue 1: bf16 h1 write
    #pragma unroll
    for (int i = 0; i < 4; ++i) {
        int gr = row0 + ty * 4 + i;
        if (gr >= NN) continue;
        ushort4 u;
        u.x = f2bf(acc[i][0]); u.y = f2bf(acc[i][1]);
        u.z = f2bf(acc[i][2]); u.w = f2bf(acc[i][3]);
        *(ushort4*)&h1b[(long)gr * 128 + col0 + tx * 4] = u;
    }
    // epilogue 2: attention dots. this thread's 4 cols live in one head.
    int head = (col0 >> 5) + (tx >> 3);          // col0 in {0,64} -> heads {0,1} or {2,3}
    int cl = (tx & 7) * 4;                       // local col within head
    float wS0 = attS[head * 32 + cl + 0], wS1 = attS[head * 32 + cl + 1];
    float wS2 = attS[head * 32 + cl + 2], wS3 = attS[head * 32 + cl + 3];
    float wD0 = attD[head * 32 + cl + 0], wD1 = attD[head * 32 + cl + 1];
    float wD2 = attD[head * 32 + cl + 2], wD3 = attD[head * 32 + cl + 3];
    float ps[4], pd[4];
    #pragma unroll
    for (int i = 0; i < 4; ++i) {
        ps[i] = acc[i][0] * wS0 + acc[i][1] * wS1 + acc[i][2] * wS2 + acc[i][3] * wS3;
        pd[i] = acc[i][0] * wD0 + acc[i][1] * wD1 + acc[i][2] * wD2 + acc[i][3] * wD3;
    }
    #pragma unroll
    for (int off = 1; off < 8; off <<= 1) {
        #pragma unroll
        for (int i = 0; i < 4; ++i) {
            ps[i] += __shfl_xor(ps[i], off);
            pd[i] += __shfl_xor(pd[i], off);
        }
    }
    if ((tx & 7) == 0) {
        #pragma unroll
        for (int i = 0; i < 4; ++i) {
            int gr = row0 + ty * 4 + i;
            if (gr < NN) {
                aS[gr * 4 + head] = ps[i];
                aD[gr * 4 + head] = pd[i];
            }
        }
    }
}

// ================= CSR build: two-level counting sort =================
__global__ void bhist_k(const int* __restrict__ srcA, const int* __restrict__ dstA,
                        int* __restrict__ bcnt_d, int* __restrict__ bcnt_s) {
    __shared__ int hd[NB], hs[NB];
    for (int i = threadIdx.x; i < NB; i += 256) { hd[i] = 0; hs[i] = 0; }
    __syncthreads();
    int e0 = blockIdx.x * CHUNK;
    int e1 = min(e0 + CHUNK, ETOT);
    for (int e = e0 + threadIdx.x; e < e1; e += 256) {
        int s, d;
        if (e < NE) { s = srcA[e]; d = dstA[e]; } else { s = d = e - NE; }
        atomicAdd(&hd[d >> SHIFT], 1);
        atomicAdd(&hs[s >> SHIFT], 1);
    }
    __syncthreads();
    for (int i = threadIdx.x; i < NB; i += 256) {
        if (hd[i]) atomicAdd(&bcnt_d[i], hd[i]);
        if (hs[i]) atomicAdd(&bcnt_s[i], hs[i]);
    }
}

__global__ void bscan_k(const int* __restrict__ bcnt_d, int* __restrict__ boffs_d,
                        int* __restrict__ bcur_d, int* __restrict__ noffs_d,
                        const int* __restrict__ bcnt_s, int* __restrict__ boffs_s,
                        int* __restrict__ bcur_s, int* __restrict__ noffs_s) {
    const int* bcnt = blockIdx.x ? bcnt_s : bcnt_d;
    int* boffs = blockIdx.x ? boffs_s : boffs_d;
    int* bcur  = blockIdx.x ? bcur_s : bcur_d;
    int* noffs = blockIdx.x ? noffs_s : noffs_d;
    __shared__ int v[512];
    int t = threadIdx.x;
    int x = (t < NB) ? bcnt[t] : 0;
    v[t] = x;
    __syncthreads();
    for (int dd = 1; dd < 512; dd <<= 1) {
        int y = (t >= dd) ? v[t - dd] : 0;
        __syncthreads();
        v[t] += y;
        __syncthreads();
    }
    if (t < NB) { int o = v[t] - x; boffs[t] = o; bcur[t] = o; }
    if (t == NB - 1) boffs[NB] = v[t];
    if (t == 0) noffs[NN] = ETOT;
}

// pack: (local_key << 16) | node_payload   (NN < 65536, local key < 128)
__global__ void part_k(const int* __restrict__ srcA, const int* __restrict__ dstA,
                       int* __restrict__ bcur_d, int* __restrict__ bcur_s,
                       int* __restrict__ pr_d, int* __restrict__ pr_s) {
    __shared__ int hd[NB], hs[NB], bd[NB], bs[NB];
    for (int i = threadIdx.x; i < NB; i += 256) { hd[i] = 0; hs[i] = 0; }
    __syncthreads();
    int e0 = blockIdx.x * CHUNK;
    int e1 = min(e0 + CHUNK, ETOT);
    for (int e = e0 + threadIdx.x; e < e1; e += 256) {
        int s, d;
        if (e < NE) { s = srcA[e]; d = dstA[e]; } else { s = d = e - NE; }
        atomicAdd(&hd[d >> SHIFT], 1);
        atomicAdd(&hs[s >> SHIFT], 1);
    }
    __syncthreads();
    for (int i = threadIdx.x; i < NB; i += 256) {
        if (hd[i]) { bd[i] = atomicAdd(&bcur_d[i], hd[i]); hd[i] = 0; }
        if (hs[i]) { bs[i] = atomicAdd(&bcur_s[i], hs[i]); hs[i] = 0; }
    }
    __syncthreads();
    for (int e = e0 + threadIdx.x; e < e1; e += 256) {
        int s, d;
        if (e < NE) { s = srcA[e]; d = dstA[e]; } else { s = d = e - NE; }
        int kd = d >> SHIFT;
        pr_d[bd[kd] + atomicAdd(&hd[kd], 1)] = ((d & (NPB - 1)) << 16) | s;
        int ks = s >> SHIFT;
        pr_s[bs[ks] + atomicAdd(&hs[ks], 1)] = ((s & (NPB - 1)) << 16) | d;
    }
}

__global__ void fine_k(const int* __restrict__ pr, const int* __restrict__ boffs,
                       int* __restrict__ noffs, int* __restrict__ csr) {
    __shared__ int cnt[NPB], off[NPB];
    int bkt = blockIdx.x;
    int n0 = bkt << SHIFT;
    int base = boffs[bkt], end = boffs[bkt + 1];
    int t = threadIdx.x;
    if (t < NPB) cnt[t] = 0;
    __syncthreads();
    for (int i = base + t; i < end; i += 256)
        atomicAdd(&cnt[pr[i] >> 16], 1);
    __syncthreads();
    if (t < NPB) off[t] = cnt[t];
    __syncthreads();
    for (int dd = 1; dd < NPB; dd <<= 1) {
        int y = 0;
        if (t < NPB && t >= dd) y = off[t - dd];
        __syncthreads();
        if (t < NPB) off[t] += y;
        __syncthreads();
    }
    if (t < NPB) {
        int excl = off[t] - cnt[t];
        int n = n0 + t;
        if (n < NN) noffs[n] = base + excl;
        off[t] = excl;
        cnt[t] = 0;
    }
    __syncthreads();
    for (int i = base + t; i < end; i += 256) {
        int p = pr[i];
        int j = p >> 16;
        int pos = base + off[j] + atomicAdd(&cnt[j], 1);
        csr[pos] = p & 0xFFFF;
    }
}

// online (max, sum-of-exp)
__device__ __forceinline__ void osm_upd(float& m, float& s, float e) {
    float nm = fmaxf(m, e);
    s = s * __expf(m - nm) + __expf(e - nm);
    m = nm;
}
__device__ __forceinline__ void osm_red(float& m, float& s) {
    #pragma unroll
    for (int off = 32; off; off >>= 1) {
        float om = __shfl_xor(m, off);
        float os = __shfl_xor(s, off);
        float nm = fmaxf(m, om);
        s = s * __expf(m - nm) + os * __expf(om - nm);
        m = nm;
    }
}

// --- layer-1: softmax + bf16 gather + bias/BN/ELU + fused layer-2 att dots -----
__global__ void gather1_k(const int* __restrict__ csr_src, const int* __restrict__ offsets,
                          const float* __restrict__ aS, const float* __restrict__ aD,
                          const unsigned short* __restrict__ h1b, const float* __restrict__ b1,
                          const float* __restrict__ bg, const float* __restrict__ bb,
                          const float* __restrict__ va_s, const float* __restrict__ va_d,
                          float* __restrict__ x2, float* __restrict__ aS2,
                          float* __restrict__ aD2) {
    __shared__ float4 wst[4][64];
    __shared__ int    sst[4][64];
    int wv = threadIdx.x >> 6;
    int d = (blockIdx.x << 2) + wv;
    if (d >= NN) return;
    int lane = threadIdx.x & 63;
    float4 ad4 = *(const float4*)&aD[d * 4];
    int o0 = offsets[d], o1 = offsets[d + 1];
    float m0 = NEG_SENT, m1 = NEG_SENT, m2 = NEG_SENT, m3 = NEG_SENT;
    float s0 = 0.f, s1 = 0.f, s2 = 0.f, s3 = 0.f;
    for (int o = o0 + lane; o < o1; o += 64) {
        int s = csr_src[o];
        float4 as4 = *(const float4*)&aS[s * 4];
        osm_upd(m0, s0, leaky02(as4.x + ad4.x));
        osm_upd(m1, s1, leaky02(as4.y + ad4.y));
        osm_upd(m2, s2, leaky02(as4.z + ad4.z));
        osm_upd(m3, s3, leaky02(as4.w + ad4.w));
    }
    osm_red(m0, s0); osm_red(m1, s1); osm_red(m2, s2); osm_red(m3, s3);
    float i0 = 1.f / (s0 + 1e-16f), i1 = 1.f / (s1 + 1e-16f);
    float i2 = 1.f / (s2 + 1e-16f), i3 = 1.f / (s3 + 1e-16f);

    int c = lane * 2;
    int head = c >> 5;
    float acc0 = 0.f, acc1 = 0.f;
    for (int base = o0; base < o1; base += 64) {
        int e = base + lane;
        if (e < o1) {
            int s = csr_src[e];
            float4 as4 = *(const float4*)&aS[s * 4];
            float4 w;
            w.x = __expf(leaky02(as4.x + ad4.x) - m0) * i0;
            w.y = __expf(leaky02(as4.y + ad4.y) - m1) * i1;
            w.z = __expf(leaky02(as4.z + ad4.z) - m2) * i2;
            w.w = __expf(leaky02(as4.w + ad4.w) - m3) * i3;
            wst[wv][lane] = w;
            sst[wv][lane] = s;
        }
        __threadfence_block();
        int lim = min(64, o1 - base);
        for (int i = 0; i < lim; ++i) {
            float w = ((const float*)&wst[wv][i])[head];
            int s = sst[wv][i];
            unsigned int hv = *(const unsigned int*)&h1b[(long)s * 128 + c];
            acc0 += w * __uint_as_float((hv & 0xFFFFu) << 16);
            acc1 += w * __uint_as_float(hv & 0xFFFF0000u);
        }
    }
    float v0 = (acc0 + b1[c]) * BN_K * bg[c] + bb[c];
    float v1 = (acc1 + b1[c + 1]) * BN_K * bg[c + 1] + bb[c + 1];
    v0 = v0 > 0.f ? v0 : __expf(v0) - 1.f;
    v1 = v1 > 0.f ? v1 : __expf(v1) - 1.f;
    *(float2*)&x2[(long)d * 128 + c] = make_float2(v0, v1);

    // fused layer-2 attention dots: aS2[d,h] = x2[d,:] . va_s[h,:]
    float r[8];
    #pragma unroll
    for (int h = 0; h < 4; ++h) {
        float2 vs = *(const float2*)&va_s[h * 128 + c];
        float2 vd = *(const float2*)&va_d[h * 128 + c];
        r[h]     = v0 * vs.x + v1 * vs.y;
        r[4 + h] = v0 * vd.x + v1 * vd.y;
    }
    #pragma unroll
    for (int off = 32; off; off >>= 1) {
        #pragma unroll
        for (int j = 0; j < 8; ++j) r[j] += __shfl_xor(r[j], off);
    }
    if (lane == 0) {
        *(float4*)&aS2[d * 4] = make_float4(r[0], r[1], r[2], r[3]);
        *(float4*)&aD2[d * 4] = make_float4(r[4], r[5], r[6], r[7]);
    }
}

// ---------------- layer-2 folding: va = W2^T att2 ----------------
__global__ void fold_k(const float* __restrict__ W2, const float* __restrict__ as2,
                       const float* __restrict__ ad2, float* __restrict__ va_s,
                       float* __restrict__ va_d) {
    int h = blockIdx.x;        // 4
    int k = threadIdx.x;       // 128
    const float* wrow = W2 + (long)k * 512 + h * 128;
    float accs = 0.f, accd = 0.f;
    for (int ci = 0; ci < 128; ++ci) {
        float w = wrow[ci];
        accs += w * as2[h * 128 + ci];
        accd += w * ad2[h * 128 + ci];
    }
    va_s[h * 128 + k] = accs;
    va_d[h * 128 + k] = accd;
}

// ---- layer-2: per-dst max/sum -> adL = {ad4, L4} with L = m + log(s+eps) ------
__global__ void dmaxsum_k(const int* __restrict__ csr_src, const int* __restrict__ offsets,
                          const float* __restrict__ aS, const float* __restrict__ aD,
                          float* __restrict__ adL) {
    int d = (blockIdx.x << 2) + (threadIdx.x >> 6);
    if (d >= NN) return;
    int lane = threadIdx.x & 63;
    float4 ad4 = *(const float4*)&aD[d * 4];
    int o0 = offsets[d], o1 = offsets[d + 1];
    float m0 = NEG_SENT, m1 = NEG_SENT, m2 = NEG_SENT, m3 = NEG_SENT;
    float s0 = 0.f, s1 = 0.f, s2 = 0.f, s3 = 0.f;
    for (int o = o0 + lane; o < o1; o += 64) {
        int s = csr_src[o];
        float4 as4 = *(const float4*)&aS[s * 4];
        osm_upd(m0, s0, leaky02(as4.x + ad4.x));
        osm_upd(m1, s1, leaky02(as4.y + ad4.y));
        osm_upd(m2, s2, leaky02(as4.z + ad4.z));
        osm_upd(m3, s3, leaky02(as4.w + ad4.w));
    }
    osm_red(m0, s0); osm_red(m1, s1); osm_red(m2, s2); osm_red(m3, s3);
    if (lane == 0) {
        *(float4*)&adL[d * 8]     = ad4;
        *(float4*)&adL[d * 8 + 4] = make_float4(m0 + __logf(s0 + 1e-16f),
                                                m1 + __logf(s1 + 1e-16f),
                                                m2 + __logf(s2 + 1e-16f),
                                                m3 + __logf(s3 + 1e-16f));
    }
}

// ---------------- layer-2: per-src weight via src-CSR ----------------
__global__ void waccg_k(const int* __restrict__ csr_dst, const int* __restrict__ offsetsS,
                        const float* __restrict__ aS, const float* __restrict__ adL,
                        float* __restrict__ Wacc) {
    int s = (blockIdx.x << 2) + (threadIdx.x >> 6);
    if (s >= NN) return;
    int lane = threadIdx.x & 63;
    float4 as4 = *(const float4*)&aS[s * 4];
    int o0 = offsetsS[s], o1 = offsetsS[s + 1];
    float a0 = 0.f, a1 = 0.f, a2 = 0.f, a3 = 0.f;
    for (int o = o0 + lane; o < o1; o += 64) {
        int d = csr_dst[o];
        float4 ad4 = *(const float4*)&adL[d * 8];
        float4 L4  = *(const float4*)&adL[d * 8 + 4];
        a0 += __expf(leaky02(as4.x + ad4.x) - L4.x);
        a1 += __expf(leaky02(as4.y + ad4.y) - L4.y);
        a2 += __expf(leaky02(as4.z + ad4.z) - L4.z);
        a3 += __expf(leaky02(as4.w + ad4.w) - L4.w);
    }
    #pragma unroll
    for (int off = 32; off; off >>= 1) {
        a0 += __shfl_xor(a0, off);
        a1 += __shfl_xor(a1, off);
        a2 += __shfl_xor(a2, off);
        a3 += __shfl_xor(a3, off);
    }
    if (lane == 0) {
        const float scale = 0.25f / (float)NN;
        *(float4*)&Wacc[s * 4] = make_float4(scale * a0, scale * a1, scale * a2, scale * a3);
    }
}

// y[h,k] = sum_r Wacc[r,h] * x2[r,k]
__global__ void yacc_k(const float* __restrict__ Wacc, const float* __restrict__ x2,
                       float* __restrict__ y) {
    int k = threadIdx.x;  // 128
    float a0 = 0.f, a1 = 0.f, a2 = 0.f, a3 = 0.f;
    for (int r = blockIdx.x; r < NN; r += gridDim.x) {
        float4 w = *(const float4*)&Wacc[r * 4];
        float x = x2[(long)r * 128 + k];
        a0 += w.x * x; a1 += w.y * x; a2 += w.z * x; a3 += w.w * x;
    }
    atomicAdd(&y[0 * 128 + k], a0);
    atomicAdd(&y[1 * 128 + k], a1);
    atomicAdd(&y[2 * 128 + k], a2);
    atomicAdd(&y[3 * 128 + k], a3);
}

__global__ void final2_k(const float* __restrict__ y, const float* __restrict__ W2,
                         const float* __restrict__ b2, const float* __restrict__ oW,
                         const float* __restrict__ ob, float* __restrict__ out) {
    __shared__ float xm[128];
    int c = threadIdx.x;
    float t = b2[c];
    #pragma unroll
    for (int h = 0; h < 4; ++h) {
        const float* yh = y + h * 128;
        for (int k = 0; k < 128; ++k) t += yh[k] * W2[(long)k * 512 + h * 128 + c];
    }
    xm[c] = t;
    __syncthreads();
    float acc = ob[c];
    for (int k = 0; k < 128; ++k) acc += xm[k] * oW[k * 128 + c];
    out[c] = acc > 0.f ? acc : 0.f;
}

extern "C" void kernel_launch(void* const* d_in, const int* in_sizes, int n_in,
                              void* d_out, int out_size, void* d_ws, size_t ws_size,
                              hipStream_t stream) {
    const float* x0  = (const float*)d_in[0];
    const int*   ei  = (const int*)d_in[1];
    const float* pW  = (const float*)d_in[2];
    const float* pb  = (const float*)d_in[3];
    const float* W1  = (const float*)d_in[4];
    const float* as1 = (const float*)d_in[5];
    const float* ad1 = (const float*)d_in[6];
    const float* b1  = (const float*)d_in[7];
    const float* bg  = (const float*)d_in[8];
    const float* bb  = (const float*)d_in[9];
    const float* W2  = (const float*)d_in[10];
    const float* as2 = (const float*)d_in[11];
    const float* ad2 = (const float*)d_in[12];
    const float* b2  = (const float*)d_in[13];
    const float* oW  = (const float*)d_in[14];
    const float* ob  = (const float*)d_in[15];
    float* out = (float*)d_out;

    float* ws = (float*)d_ws;
    float* x1    = ws; ws += 6400000;      // [N,128] fp32
    float* x2    = ws; ws += 6400000;      // [N,128] fp32
    unsigned short* h1b = (unsigned short*)ws; ws += 3200000;  // [N,128] bf16
    float* aS1   = ws; ws += 200000;
    float* aD1   = ws; ws += 200000;
    float* aS2   = ws; ws += 200000;
    float* aD2   = ws; ws += 200000;
    float* adL   = ws; ws += 400000;
    float* Wacc  = ws; ws += 200000;
    float* va_s  = ws; ws += 512;
    float* va_d  = ws; ws += 512;
    float* y     = ws; ws += 512;
    int* bcnt_d  = (int*)ws; ws += NB;
    int* boffs_d = (int*)ws; ws += NB + 1;
    int* bcur_d  = (int*)ws; ws += NB;
    int* bcnt_s  = (int*)ws; ws += NB;
    int* boffs_s = (int*)ws; ws += NB + 1;
    int* bcur_s  = (int*)ws; ws += NB;
    int* offs_d  = (int*)ws; ws += NN + 1;
    int* offs_s  = (int*)ws; ws += NN + 1;
    int* csr_src = (int*)ws; ws += ETOT;
    int* csr_dst = (int*)ws; ws += ETOT;
    int* pr_d    = (int*)ws; ws += ETOT;
    int* pr_s    = (int*)ws; ws += ETOT;

    const int* srcA = ei;
    const int* dstA = ei + NE;

    hipMemsetAsync(bcnt_d, 0, (size_t)NB * 4, stream);
    hipMemsetAsync(bcnt_s, 0, (size_t)NB * 4, stream);
    hipMemsetAsync(y, 0, (size_t)512 * 4, stream);

    dim3 blk(256);

    // CSR builds (two-level counting sort, packed pairs)
    bhist_k<<<PGRID, blk, 0, stream>>>(srcA, dstA, bcnt_d, bcnt_s);
    bscan_k<<<2, 512, 0, stream>>>(bcnt_d, boffs_d, bcur_d, offs_d,
                                   bcnt_s, boffs_s, bcur_s, offs_s);
    part_k<<<PGRID, blk, 0, stream>>>(srcA, dstA, bcur_d, bcur_s, pr_d, pr_s);
    fine_k<<<NB, blk, 0, stream>>>(pr_d, boffs_d, offs_d, csr_src);
    fine_k<<<NB, blk, 0, stream>>>(pr_s, boffs_s, offs_s, csr_dst);

    // layer 0/1
    gemm_k128<1><<<dim3(782, 2), blk, 0, stream>>>(x0, pW, pb, x1, NN, 128);
    gemm2_k<<<dim3(782, 2), blk, 0, stream>>>(x1, W1, as1, ad1, h1b, aS1, aD1);
    fold_k<<<4, 128, 0, stream>>>(W2, as2, ad2, va_s, va_d);
    gather1_k<<<12500, blk, 0, stream>>>(csr_src, offs_d, aS1, aD1, h1b, b1, bg, bb,
                                         va_s, va_d, x2, aS2, aD2);

    // layer 2 (h2 never materialized)
    dmaxsum_k<<<12500, blk, 0, stream>>>(csr_src, offs_d, aS2, aD2, adL);
    waccg_k<<<12500, blk, 0, stream>>>(csr_dst, offs_s, aS2, adL, Wacc);
    yacc_k<<<256, 128, 0, stream>>>(Wacc, x2, y);
    final2_k<<<1, 128, 0, stream>>>(y, W2, b2, oW, ob, out);
}

// Round 8
// 473.915 us; speedup vs baseline: 9.1341x; 1.0004x over previous
//
#include <hip/hip_runtime.h>
#include <hip/hip_bf16.h>

#define NN 50000
#define NROW 50048                     // 391 * 128 padded rows
#define NE 1600000
#define ETOT (NE + NN)                 // 1,650,000 (self-loops appended)
#define BN_K 0.9999950000374997f
#define NEG_SENT -1e30f

#define SHIFT 7
#define NPB 128
#define NB ((NN + NPB - 1) >> SHIFT)   // 391
#define CHUNK 4096
#define PGRID ((ETOT + CHUNK - 1) / CHUNK)

typedef __bf16 bf16x8 __attribute__((ext_vector_type(8)));
typedef float f32x4 __attribute__((ext_vector_type(4)));

__device__ __forceinline__ float leaky02(float x) { return x > 0.f ? x : 0.2f * x; }

__device__ __forceinline__ unsigned short f2bf(float f) {
    unsigned int u = __float_as_uint(f);
    u += 0x7FFFu + ((u >> 16) & 1u);
    return (unsigned short)(u >> 16);
}

// ---------------- prep: x0 -> bf16 (padded rows zeroed) ----------------
__global__ void cvt_k(const float* __restrict__ x0, unsigned short* __restrict__ x0b) {
    int g = blockIdx.x * 256 + threadIdx.x;      // float4 index
    if (g >= NROW * 32) return;
    int row = g >> 5;
    float4 v = make_float4(0.f, 0.f, 0.f, 0.f);
    if (row < NN) v = *(const float4*)&x0[(long)g * 4];
    ushort4 u;
    u.x = f2bf(v.x); u.y = f2bf(v.y); u.z = f2bf(v.z); u.w = f2bf(v.w);
    *(ushort4*)&x0b[(long)g * 4] = u;
}

// ---------------- prep: transpose weights to [N][K] bf16 ----------------
__global__ void prepw_k(const float* __restrict__ pW, const float* __restrict__ W1,
                        unsigned short* __restrict__ pWt, unsigned short* __restrict__ W1t) {
    const float* in = blockIdx.x ? W1 : pW;
    unsigned short* outp = blockIdx.x ? W1t : pWt;
    for (int i = threadIdx.x; i < 16384; i += 256) {
        int n = i & 127, k = i >> 7;
        outp[n * 128 + k] = f2bf(in[k * 128 + n]);
    }
}

// ---- fused MFMA chain: x1 = relu(x0@pW+pb); h1 = x1@W1 (bf16) + att dots ----
__global__ __launch_bounds__(256) void fgemm_k(
    const unsigned short* __restrict__ x0b, const unsigned short* __restrict__ pWt,
    const unsigned short* __restrict__ W1t, const float* __restrict__ pb,
    const float* __restrict__ attS, const float* __restrict__ attD,
    unsigned short* __restrict__ h1b, float* __restrict__ aS, float* __restrict__ aD) {
    __shared__ unsigned short x1s[128][136];     // 272B row stride (16B aligned)
    const int tid = threadIdx.x;
    const int wv = tid >> 6, l = tid & 63;
    const int lr = l & 15, lg = l >> 4;
    const int r0 = blockIdx.x * 128;
    const int wr = wv * 32;

    bf16x8 Af[2][4];
    f32x4 acc[2][8];

    // ---- GEMM1 ----
    #pragma unroll
    for (int rt = 0; rt < 2; ++rt)
        #pragma unroll
        for (int kt = 0; kt < 4; ++kt)
            Af[rt][kt] = *(const bf16x8*)&x0b[(long)(r0 + wr + rt * 16 + lr) * 128 + kt * 32 + lg * 8];
    #pragma unroll
    for (int rt = 0; rt < 2; ++rt)
        #pragma unroll
        for (int ct = 0; ct < 8; ++ct)
            acc[rt][ct] = (f32x4){0.f, 0.f, 0.f, 0.f};
    #pragma unroll
    for (int ct = 0; ct < 8; ++ct) {
        bf16x8 Bf[4];
        #pragma unroll
        for (int kt = 0; kt < 4; ++kt)
            Bf[kt] = *(const bf16x8*)&pWt[(ct * 16 + lr) * 128 + kt * 32 + lg * 8];
        #pragma unroll
        for (int kt = 0; kt < 4; ++kt) {
            acc[0][ct] = __builtin_amdgcn_mfma_f32_16x16x32_bf16(Af[0][kt], Bf[kt], acc[0][ct], 0, 0, 0);
            acc[1][ct] = __builtin_amdgcn_mfma_f32_16x16x32_bf16(Af[1][kt], Bf[kt], acc[1][ct], 0, 0, 0);
        }
    }
    #pragma unroll
    for (int ct = 0; ct < 8; ++ct) {
        int col = ct * 16 + lr;
        float bv = pb[col];
        #pragma unroll
        for (int rt = 0; rt < 2; ++rt)
            #pragma unroll
            for (int r = 0; r < 4; ++r) {
                float v = acc[rt][ct][r] + bv;
                x1s[wr + rt * 16 + lg * 4 + r][col] = f2bf(v > 0.f ? v : 0.f);
            }
    }
    __syncthreads();

    // ---- GEMM2 ----
    #pragma unroll
    for (int rt = 0; rt < 2; ++rt)
        #pragma unroll
        for (int kt = 0; kt < 4; ++kt)
            Af[rt][kt] = *(const bf16x8*)&x1s[wr + rt * 16 + lr][kt * 32 + lg * 8];
    #pragma unroll
    for (int rt = 0; rt < 2; ++rt)
        #pragma unroll
        for (int ct = 0; ct < 8; ++ct)
            acc[rt][ct] = (f32x4){0.f, 0.f, 0.f, 0.f};
    #pragma unroll
    for (int ct = 0; ct < 8; ++ct) {
        bf16x8 Bf[4];
        #pragma unroll
        for (int kt = 0; kt < 4; ++kt)
            Bf[kt] = *(const bf16x8*)&W1t[(ct * 16 + lr) * 128 + kt * 32 + lg * 8];
        #pragma unroll
        for (int kt = 0; kt < 4; ++kt) {
            acc[0][ct] = __builtin_amdgcn_mfma_f32_16x16x32_bf16(Af[0][kt], Bf[kt], acc[0][ct], 0, 0, 0);
            acc[1][ct] = __builtin_amdgcn_mfma_f32_16x16x32_bf16(Af[1][kt], Bf[kt], acc[1][ct], 0, 0, 0);
        }
    }
    __syncthreads();                              // all waves done reading x1s
    #pragma unroll
    for (int ct = 0; ct < 8; ++ct)
        #pragma unroll
        for (int rt = 0; rt < 2; ++rt)
            #pragma unroll
            for (int r = 0; r < 4; ++r)
                x1s[wr + rt * 16 + lg * 4 + r][ct * 16 + lr] = f2bf(acc[rt][ct][r]);
    __syncthreads();

    // ---- copy out (coalesced) + fused attention dots ----
    #pragma unroll
    for (int i = 0; i < 8; ++i) {
        int idx = tid + i * 256;
        int row = idx >> 4, cc = idx & 15;
        bf16x8 hv = *(const bf16x8*)&x1s[row][cc * 8];
        *(bf16x8*)&h1b[(long)(r0 + row) * 128 + cc * 8] = hv;
        int head = cc >> 2, lc = (cc & 3) * 8;
        float ps = 0.f, pd = 0.f;
        #pragma unroll
        for (int j = 0; j < 8; ++j) {
            float v = (float)hv[j];
            ps += v * attS[head * 32 + lc + j];
            pd += v * attD[head * 32 + lc + j];
        }
        ps += __shfl_xor(ps, 1); ps += __shfl_xor(ps, 2);
        pd += __shfl_xor(pd, 1); pd += __shfl_xor(pd, 2);
        if ((cc & 3) == 0) {
            aS[(r0 + row) * 4 + head] = ps;
            aD[(r0 + row) * 4 + head] = pd;
        }
    }
}

// ================= CSR build: two-level counting sort =================
__global__ void bhist_k(const int* __restrict__ srcA, const int* __restrict__ dstA,
                        int* __restrict__ bcnt_d, int* __restrict__ bcnt_s) {
    __shared__ int hd[NB], hs[NB];
    for (int i = threadIdx.x; i < NB; i += 256) { hd[i] = 0; hs[i] = 0; }
    __syncthreads();
    int e0 = blockIdx.x * CHUNK;
    int e1 = min(e0 + CHUNK, ETOT);
    for (int e = e0 + threadIdx.x; e < e1; e += 256) {
        int s, d;
        if (e < NE) { s = srcA[e]; d = dstA[e]; } else { s = d = e - NE; }
        atomicAdd(&hd[d >> SHIFT], 1);
        atomicAdd(&hs[s >> SHIFT], 1);
    }
    __syncthreads();
    for (int i = threadIdx.x; i < NB; i += 256) {
        if (hd[i]) atomicAdd(&bcnt_d[i], hd[i]);
        if (hs[i]) atomicAdd(&bcnt_s[i], hs[i]);
    }
}

__global__ void bscan_k(const int* __restrict__ bcnt_d, int* __restrict__ boffs_d,
                        int* __restrict__ bcur_d, int* __restrict__ noffs_d,
                        const int* __restrict__ bcnt_s, int* __restrict__ boffs_s,
                        int* __restrict__ bcur_s, int* __restrict__ noffs_s) {
    const int* bcnt = blockIdx.x ? bcnt_s : bcnt_d;
    int* boffs = blockIdx.x ? boffs_s : boffs_d;
    int* bcur  = blockIdx.x ? bcur_s : bcur_d;
    int* noffs = blockIdx.x ? noffs_s : noffs_d;
    __shared__ int v[512];
    int t = threadIdx.x;
    int x = (t < NB) ? bcnt[t] : 0;
    v[t] = x;
    __syncthreads();
    for (int dd = 1; dd < 512; dd <<= 1) {
        int y = (t >= dd) ? v[t - dd] : 0;
        __syncthreads();
        v[t] += y;
        __syncthreads();
    }
    if (t < NB) { int o = v[t] - x; boffs[t] = o; bcur[t] = o; }
    if (t == NB - 1) boffs[NB] = v[t];
    if (t == 0) noffs[NN] = ETOT;
}

__global__ void part_k(const int* __restrict__ srcA, const int* __restrict__ dstA,
                       int* __restrict__ bcur_d, int* __restrict__ bcur_s,
                       int* __restrict__ pr_d, int* __restrict__ pr_s) {
    __shared__ int hd[NB], hs[NB], bd[NB], bs[NB];
    for (int i = threadIdx.x; i < NB; i += 256) { hd[i] = 0; hs[i] = 0; }
    __syncthreads();
    int e0 = blockIdx.x * CHUNK;
    int e1 = min(e0 + CHUNK, ETOT);
    for (int e = e0 + threadIdx.x; e < e1; e += 256) {
        int s, d;
        if (e < NE) { s = srcA[e]; d = dstA[e]; } else { s = d = e - NE; }
        atomicAdd(&hd[d >> SHIFT], 1);
        atomicAdd(&hs[s >> SHIFT], 1);
    }
    __syncthreads();
    for (int i = threadIdx.x; i < NB; i += 256) {
        if (hd[i]) { bd[i] = atomicAdd(&bcur_d[i], hd[i]); hd[i] = 0; }
        if (hs[i]) { bs[i] = atomicAdd(&bcur_s[i], hs[i]); hs[i] = 0; }
    }
    __syncthreads();
    for (int e = e0 + threadIdx.x; e < e1; e += 256) {
        int s, d;
        if (e < NE) { s = srcA[e]; d = dstA[e]; } else { s = d = e - NE; }
        int kd = d >> SHIFT;
        pr_d[bd[kd] + atomicAdd(&hd[kd], 1)] = ((d & (NPB - 1)) << 16) | s;
        int ks = s >> SHIFT;
        pr_s[bs[ks] + atomicAdd(&hs[ks], 1)] = ((s & (NPB - 1)) << 16) | d;
    }
}

__global__ void fine_k(const int* __restrict__ pr, const int* __restrict__ boffs,
                       int* __restrict__ noffs, int* __restrict__ csr) {
    __shared__ int cnt[NPB], off[NPB];
    int bkt = blockIdx.x;
    int n0 = bkt << SHIFT;
    int base = boffs[bkt], end = boffs[bkt + 1];
    int t = threadIdx.x;
    if (t < NPB) cnt[t] = 0;
    __syncthreads();
    for (int i = base + t; i < end; i += 256)
        atomicAdd(&cnt[pr[i] >> 16], 1);
    __syncthreads();
    if (t < NPB) off[t] = cnt[t];
    __syncthreads();
    for (int dd = 1; dd < NPB; dd <<= 1) {
        int y = 0;
        if (t < NPB && t >= dd) y = off[t - dd];
        __syncthreads();
        if (t < NPB) off[t] += y;
        __syncthreads();
    }
    if (t < NPB) {
        int excl = off[t] - cnt[t];
        int n = n0 + t;
        if (n < NN) noffs[n] = base + excl;
        off[t] = excl;
        cnt[t] = 0;
    }
    __syncthreads();
    for (int i = base + t; i < end; i += 256) {
        int p = pr[i];
        int j = p >> 16;
        int pos = base + off[j] + atomicAdd(&cnt[j], 1);
        csr[pos] = p & 0xFFFF;
    }
}

// online (max, sum-of-exp)
__device__ __forceinline__ void osm_upd(float& m, float& s, float e) {
    float nm = fmaxf(m, e);
    s = s * __expf(m - nm) + __expf(e - nm);
    m = nm;
}
__device__ __forceinline__ void osm_red(float& m, float& s) {
    #pragma unroll
    for (int off = 32; off; off >>= 1) {
        float om = __shfl_xor(m, off);
        float os = __shfl_xor(s, off);
        float nm = fmaxf(m, om);
        s = s * __expf(m - nm) + os * __expf(om - nm);
        m = nm;
    }
}

// --- layer-1: softmax + bf16 gather + bias/BN/ELU + fused layer-2 att dots -----
__global__ void gather1_k(const int* __restrict__ csr_src, const int* __restrict__ offsets,
                          const float* __restrict__ aS, const float* __restrict__ aD,
                          const unsigned short* __restrict__ h1b, const float* __restrict__ b1,
                          const float* __restrict__ bg, const float* __restrict__ bb,
                          const float* __restrict__ va_s, const float* __restrict__ va_d,
                          unsigned short* __restrict__ x2b, float* __restrict__ aS2,
                          float* __restrict__ aD2) {
    __shared__ float4 wst[4][64];
    __shared__ int    sst[4][64];
    int wv = threadIdx.x >> 6;
    int d = (blockIdx.x << 2) + wv;
    if (d >= NN) return;
    int lane = threadIdx.x & 63;
    float4 ad4 = *(const float4*)&aD[d * 4];
    int o0 = offsets[d], o1 = offsets[d + 1];
    float m0 = NEG_SENT, m1 = NEG_SENT, m2 = NEG_SENT, m3 = NEG_SENT;
    float s0 = 0.f, s1 = 0.f, s2 = 0.f, s3 = 0.f;
    for (int o = o0 + lane; o < o1; o += 64) {
        int s = csr_src[o];
        float4 as4 = *(const float4*)&aS[s * 4];
        osm_upd(m0, s0, leaky02(as4.x + ad4.x));
        osm_upd(m1, s1, leaky02(as4.y + ad4.y));
        osm_upd(m2, s2, leaky02(as4.z + ad4.z));
        osm_upd(m3, s3, leaky02(as4.w + ad4.w));
    }
    osm_red(m0, s0); osm_red(m1, s1); osm_red(m2, s2); osm_red(m3, s3);
    float i0 = 1.f / (s0 + 1e-16f), i1 = 1.f / (s1 + 1e-16f);
    float i2 = 1.f / (s2 + 1e-16f), i3 = 1.f / (s3 + 1e-16f);

    int c = lane * 2;
    int head = c >> 5;
    unsigned cb = (unsigned)(c << 1);             // byte offset within row
    float acc0 = 0.f, acc1 = 0.f;
    for (int base = o0; base < o1; base += 64) {
        int e = base + lane;
        if (e < o1) {
            int s = csr_src[e];
            float4 as4 = *(const float4*)&aS[s * 4];
            float4 w;
            w.x = __expf(leaky02(as4.x + ad4.x) - m0) * i0;
            w.y = __expf(leaky02(as4.y + ad4.y) - m1) * i1;
            w.z = __expf(leaky02(as4.z + ad4.z) - m2) * i2;
            w.w = __expf(leaky02(as4.w + ad4.w) - m3) * i3;
            wst[wv][lane] = w;
            sst[wv][lane] = s << 8;               // row byte offset
        }
        __threadfence_block();
        int lim = min(64, o1 - base);
        #pragma unroll 2
        for (int i = 0; i < lim; ++i) {
            float w = ((const float*)&wst[wv][i])[head];
            unsigned hv = *(const unsigned*)((const char*)h1b + (unsigned)sst[wv][i] + cb);
            acc0 += w * __uint_as_float(hv << 16);
            acc1 += w * __uint_as_float(hv & 0xFFFF0000u);
        }
    }
    float v0 = (acc0 + b1[c]) * BN_K * bg[c] + bb[c];
    float v1 = (acc1 + b1[c + 1]) * BN_K * bg[c + 1] + bb[c + 1];
    v0 = v0 > 0.f ? v0 : __expf(v0) - 1.f;
    v1 = v1 > 0.f ? v1 : __expf(v1) - 1.f;
    *(unsigned*)&x2b[(long)d * 128 + c] = (unsigned)f2bf(v0) | ((unsigned)f2bf(v1) << 16);

    float r[8];
    #pragma unroll
    for (int h = 0; h < 4; ++h) {
        float2 vs = *(const float2*)&va_s[h * 128 + c];
        float2 vd = *(const float2*)&va_d[h * 128 + c];
        r[h]     = v0 * vs.x + v1 * vs.y;
        r[4 + h] = v0 * vd.x + v1 * vd.y;
    }
    #pragma unroll
    for (int off = 32; off; off >>= 1) {
        #pragma unroll
        for (int j = 0; j < 8; ++j) r[j] += __shfl_xor(r[j], off);
    }
    if (lane == 0) {
        *(float4*)&aS2[d * 4] = make_float4(r[0], r[1], r[2], r[3]);
        *(float4*)&aD2[d * 4] = make_float4(r[4], r[5], r[6], r[7]);
    }
}

// ---------------- layer-2 folding: va = W2^T att2 ----------------
__global__ void fold_k(const float* __restrict__ W2, const float* __restrict__ as2,
                       const float* __restrict__ ad2, float* __restrict__ va_s,
                       float* __restrict__ va_d) {
    int h = blockIdx.x;
    int k = threadIdx.x;
    const float* wrow = W2 + (long)k * 512 + h * 128;
    float accs = 0.f, accd = 0.f;
    for (int ci = 0; ci < 128; ++ci) {
        float w = wrow[ci];
        accs += w * as2[h * 128 + ci];
        accd += w * ad2[h * 128 + ci];
    }
    va_s[h * 128 + k] = accs;
    va_d[h * 128 + k] = accd;
}

// ---- layer-2: per-dst max/sum -> adL = {ad4, L4}, L = m + log(s+eps) ------
__global__ void dmaxsum_k(const int* __restrict__ csr_src, const int* __restrict__ offsets,
                          const float* __restrict__ aS, const float* __restrict__ aD,
                          float* __restrict__ adL) {
    int d = (blockIdx.x << 2) + (threadIdx.x >> 6);
    if (d >= NN) return;
    int lane = threadIdx.x & 63;
    float4 ad4 = *(const float4*)&aD[d * 4];
    int o0 = offsets[d], o1 = offsets[d + 1];
    float m0 = NEG_SENT, m1 = NEG_SENT, m2 = NEG_SENT, m3 = NEG_SENT;
    float s0 = 0.f, s1 = 0.f, s2 = 0.f, s3 = 0.f;
    for (int o = o0 + lane; o < o1; o += 64) {
        int s = csr_src[o];
        float4 as4 = *(const float4*)&aS[s * 4];
        osm_upd(m0, s0, leaky02(as4.x + ad4.x));
        osm_upd(m1, s1, leaky02(as4.y + ad4.y));
        osm_upd(m2, s2, leaky02(as4.z + ad4.z));
        osm_upd(m3, s3, leaky02(as4.w + ad4.w));
    }
    osm_red(m0, s0); osm_red(m1, s1); osm_red(m2, s2); osm_red(m3, s3);
    if (lane == 0) {
        *(float4*)&adL[d * 8]     = ad4;
        *(float4*)&adL[d * 8 + 4] = make_float4(m0 + __logf(s0 + 1e-16f),
                                                m1 + __logf(s1 + 1e-16f),
                                                m2 + __logf(s2 + 1e-16f),
                                                m3 + __logf(s3 + 1e-16f));
    }
}

// ---------------- layer-2: per-src weight via src-CSR ----------------
__global__ void waccg_k(const int* __restrict__ csr_dst, const int* __restrict__ offsetsS,
                        const float* __restrict__ aS, const float* __restrict__ adL,
                        float* __restrict__ Wacc) {
    int s = (blockIdx.x << 2) + (threadIdx.x >> 6);
    if (s >= NN) return;
    int lane = threadIdx.x & 63;
    float4 as4 = *(const float4*)&aS[s * 4];
    int o0 = offsetsS[s], o1 = offsetsS[s + 1];
    float a0 = 0.f, a1 = 0.f, a2 = 0.f, a3 = 0.f;
    for (int o = o0 + lane; o < o1; o += 64) {
        int d = csr_dst[o];
        float4 ad4 = *(const float4*)&adL[d * 8];
        float4 L4  = *(const float4*)&adL[d * 8 + 4];
        a0 += __expf(leaky02(as4.x + ad4.x) - L4.x);
        a1 += __expf(leaky02(as4.y + ad4.y) - L4.y);
        a2 += __expf(leaky02(as4.z + ad4.z) - L4.z);
        a3 += __expf(leaky02(as4.w + ad4.w) - L4.w);
    }
    #pragma unroll
    for (int off = 32; off; off >>= 1) {
        a0 += __shfl_xor(a0, off);
        a1 += __shfl_xor(a1, off);
        a2 += __shfl_xor(a2, off);
        a3 += __shfl_xor(a3, off);
    }
    if (lane == 0) {
        const float scale = 0.25f / (float)NN;
        *(float4*)&Wacc[s * 4] = make_float4(scale * a0, scale * a1, scale * a2, scale * a3);
    }
}

// y[h,k] = sum_r Wacc[r,h] * x2[r,k]  (x2 in bf16)
__global__ void yacc_k(const float* __restrict__ Wacc, const unsigned short* __restrict__ x2b,
                       float* __restrict__ y) {
    int k2 = threadIdx.x;                 // 64 threads, cols 2k2, 2k2+1
    float a[8] = {};
    for (int r = blockIdx.x; r < NN; r += gridDim.x) {
        float4 w = *(const float4*)&Wacc[r * 4];
        unsigned hv = *(const unsigned*)&x2b[(long)r * 128 + k2 * 2];
        float xl = __uint_as_float(hv << 16);
        float xh = __uint_as_float(hv & 0xFFFF0000u);
        a[0] += w.x * xl; a[1] += w.x * xh;
        a[2] += w.y * xl; a[3] += w.y * xh;
        a[4] += w.z * xl; a[5] += w.z * xh;
        a[6] += w.w * xl; a[7] += w.w * xh;
    }
    int c = k2 * 2;
    atomicAdd(&y[0 * 128 + c], a[0]); atomicAdd(&y[0 * 128 + c + 1], a[1]);
    atomicAdd(&y[1 * 128 + c], a[2]); atomicAdd(&y[1 * 128 + c + 1], a[3]);
    atomicAdd(&y[2 * 128 + c], a[4]); atomicAdd(&y[2 * 128 + c + 1], a[5]);
    atomicAdd(&y[3 * 128 + c], a[6]); atomicAdd(&y[3 * 128 + c + 1], a[7]);
}

__global__ void final2_k(const float* __restrict__ y, const float* __restrict__ W2,
                         const float* __restrict__ b2, const float* __restrict__ oW,
                         const float* __restrict__ ob, float* __restrict__ out) {
    __shared__ float xm[128];
    int c = threadIdx.x;
    float t = b2[c];
    #pragma unroll
    for (int h = 0; h < 4; ++h) {
        const float* yh = y + h * 128;
        for (int k = 0; k < 128; ++k) t += yh[k] * W2[(long)k * 512 + h * 128 + c];
    }
    xm[c] = t;
    __syncthreads();
    float acc = ob[c];
    for (int k = 0; k < 128; ++k) acc += xm[k] * oW[k * 128 + c];
    out[c] = acc > 0.f ? acc : 0.f;
}

extern "C" void kernel_launch(void* const* d_in, const int* in_sizes, int n_in,
                              void* d_out, int out_size, void* d_ws, size_t ws_size,
                              hipStream_t stream) {
    const float* x0  = (const float*)d_in[0];
    const int*   ei  = (const int*)d_in[1];
    const float* pW  = (const float*)d_in[2];
    const float* pb  = (const float*)d_in[3];
    const float* W1  = (const float*)d_in[4];
    const float* as1 = (const float*)d_in[5];
    const float* ad1 = (const float*)d_in[6];
    const float* b1  = (const float*)d_in[7];
    const float* bg  = (const float*)d_in[8];
    const float* bb  = (const float*)d_in[9];
    const float* W2  = (const float*)d_in[10];
    const float* as2 = (const float*)d_in[11];
    const float* ad2 = (const float*)d_in[12];
    const float* b2  = (const float*)d_in[13];
    const float* oW  = (const float*)d_in[14];
    const float* ob  = (const float*)d_in[15];
    float* out = (float*)d_out;

    float* ws = (float*)d_ws;
    unsigned short* x0b = (unsigned short*)ws; ws += 3203072;   // NROW*128 bf16
    unsigned short* h1b = (unsigned short*)ws; ws += 3203072;
    unsigned short* x2b = (unsigned short*)ws; ws += 3200000;   // NN*128 bf16
    unsigned short* pWt = (unsigned short*)ws; ws += 8192;
    unsigned short* W1t = (unsigned short*)ws; ws += 8192;
    float* aS1   = ws; ws += 200192;   // NROW*4
    float* aD1   = ws; ws += 200192;
    float* aS2   = ws; ws += 200000;
    float* aD2   = ws; ws += 200000;
    float* adL   = ws; ws += 400000;
    float* Wacc  = ws; ws += 200000;
    float* va_s  = ws; ws += 512;
    float* va_d  = ws; ws += 512;
    float* y     = ws; ws += 512;
    int* bcnt_d  = (int*)ws; ws += NB;
    int* boffs_d = (int*)ws; ws += NB + 1;
    int* bcur_d  = (int*)ws; ws += NB;
    int* bcnt_s  = (int*)ws; ws += NB;
    int* boffs_s = (int*)ws; ws += NB + 1;
    int* bcur_s  = (int*)ws; ws += NB;
    int* offs_d  = (int*)ws; ws += NN + 1;
    int* offs_s  = (int*)ws; ws += NN + 1;
    int* csr_src = (int*)ws; ws += ETOT;
    int* csr_dst = (int*)ws; ws += ETOT;
    int* pr_d    = (int*)ws; ws += ETOT;
    int* pr_s    = (int*)ws; ws += ETOT;

    const int* srcA = ei;
    const int* dstA = ei + NE;

    hipMemsetAsync(bcnt_d, 0, (size_t)NB * 4, stream);
    hipMemsetAsync(bcnt_s, 0, (size_t)NB * 4, stream);
    hipMemsetAsync(y, 0, (size_t)512 * 4, stream);

    dim3 blk(256);

    // prep + CSR (independent of dense chain)
    cvt_k<<<(NROW * 32 + 255) / 256, blk, 0, stream>>>(x0, x0b);
    prepw_k<<<2, blk, 0, stream>>>(pW, W1, pWt, W1t);
    bhist_k<<<PGRID, blk, 0, stream>>>(srcA, dstA, bcnt_d, bcnt_s);
    bscan_k<<<2, 512, 0, stream>>>(bcnt_d, boffs_d, bcur_d, offs_d,
                                   bcnt_s, boffs_s, bcur_s, offs_s);
    part_k<<<PGRID, blk, 0, stream>>>(srcA, dstA, bcur_d, bcur_s, pr_d, pr_s);
    fine_k<<<NB, blk, 0, stream>>>(pr_d, boffs_d, offs_d, csr_src);
    fine_k<<<NB, blk, 0, stream>>>(pr_s, boffs_s, offs_s, csr_dst);

    // fused dense chain (MFMA bf16): x1, h1, att1 dots
    fgemm_k<<<391, blk, 0, stream>>>(x0b, pWt, W1t, pb, as1, ad1, h1b, aS1, aD1);
    fold_k<<<4, 128, 0, stream>>>(W2, as2, ad2, va_s, va_d);

    // layer-1 aggregation + fused layer-2 att dots
    gather1_k<<<12500, blk, 0, stream>>>(csr_src, offs_d, aS1, aD1, h1b, b1, bg, bb,
                                         va_s, va_d, x2b, aS2, aD2);

    // layer 2 (h2 never materialized)
    dmaxsum_k<<<12500, blk, 0, stream>>>(csr_src, offs_d, aS2, aD2, adL);
    waccg_k<<<12500, blk, 0, stream>>>(csr_dst, offs_s, aS2, adL, Wacc);
    yacc_k<<<256, 64, 0, stream>>>(Wacc, x2b, y);
    final2_k<<<1, 128, 0, stream>>>(y, W2, b2, oW, ob, out);
}

// Round 9
// 451.225 us; speedup vs baseline: 9.5934x; 1.0503x over previous
//
#include <hip/hip_runtime.h>
#include <hip/hip_bf16.h>

#define NN 50000
#define NROW 50048                     // 391 * 128 padded rows
#define NE 1600000
#define ETOT (NE + NN)                 // 1,650,000 (self-loops appended)
#define BN_K 0.9999950000374997f

#define SHIFT 7
#define NPB 128
#define NB ((NN + NPB - 1) >> SHIFT)   // 391
#define CHUNK 4096
#define PGRID ((ETOT + CHUNK - 1) / CHUNK)

typedef __bf16 bf16x8 __attribute__((ext_vector_type(8)));
typedef float f32x4 __attribute__((ext_vector_type(4)));

__device__ __forceinline__ float leaky02(float x) { return x > 0.f ? x : 0.2f * x; }

__device__ __forceinline__ unsigned short f2bf(float f) {
    unsigned int u = __float_as_uint(f);
    u += 0x7FFFu + ((u >> 16) & 1u);
    return (unsigned short)(u >> 16);
}

// ---------------- prep: x0 -> bf16 (padded rows zeroed) ----------------
__global__ void cvt_k(const float* __restrict__ x0, unsigned short* __restrict__ x0b) {
    int g = blockIdx.x * 256 + threadIdx.x;      // float4 index
    if (g >= NROW * 32) return;
    int row = g >> 5;
    float4 v = make_float4(0.f, 0.f, 0.f, 0.f);
    if (row < NN) v = *(const float4*)&x0[(long)g * 4];
    ushort4 u;
    u.x = f2bf(v.x); u.y = f2bf(v.y); u.z = f2bf(v.z); u.w = f2bf(v.w);
    *(ushort4*)&x0b[(long)g * 4] = u;
}

// ---------------- prep: transpose weights to [N][K] bf16 ----------------
__global__ void prepw_k(const float* __restrict__ pW, const float* __restrict__ W1,
                        unsigned short* __restrict__ pWt, unsigned short* __restrict__ W1t) {
    const float* in = blockIdx.x ? W1 : pW;
    unsigned short* outp = blockIdx.x ? W1t : pWt;
    for (int i = threadIdx.x; i < 16384; i += 256) {
        int n = i & 127, k = i >> 7;
        outp[n * 128 + k] = f2bf(in[k * 128 + n]);
    }
}

// ---- fused MFMA chain: x1 = relu(x0@pW+pb); h1 = x1@W1 (bf16) + att dots ----
__global__ __launch_bounds__(256) void fgemm_k(
    const unsigned short* __restrict__ x0b, const unsigned short* __restrict__ pWt,
    const unsigned short* __restrict__ W1t, const float* __restrict__ pb,
    const float* __restrict__ attS, const float* __restrict__ attD,
    unsigned short* __restrict__ h1b, float* __restrict__ aS, float* __restrict__ aD) {
    __shared__ unsigned short x1s[128][136];
    const int tid = threadIdx.x;
    const int wv = tid >> 6, l = tid & 63;
    const int lr = l & 15, lg = l >> 4;
    const int r0 = blockIdx.x * 128;
    const int wr = wv * 32;

    bf16x8 Af[2][4];
    f32x4 acc[2][8];

    // ---- GEMM1 ----
    #pragma unroll
    for (int rt = 0; rt < 2; ++rt)
        #pragma unroll
        for (int kt = 0; kt < 4; ++kt)
            Af[rt][kt] = *(const bf16x8*)&x0b[(long)(r0 + wr + rt * 16 + lr) * 128 + kt * 32 + lg * 8];
    #pragma unroll
    for (int rt = 0; rt < 2; ++rt)
        #pragma unroll
        for (int ct = 0; ct < 8; ++ct)
            acc[rt][ct] = (f32x4){0.f, 0.f, 0.f, 0.f};
    #pragma unroll
    for (int ct = 0; ct < 8; ++ct) {
        bf16x8 Bf[4];
        #pragma unroll
        for (int kt = 0; kt < 4; ++kt)
            Bf[kt] = *(const bf16x8*)&pWt[(ct * 16 + lr) * 128 + kt * 32 + lg * 8];
        #pragma unroll
        for (int kt = 0; kt < 4; ++kt) {
            acc[0][ct] = __builtin_amdgcn_mfma_f32_16x16x32_bf16(Af[0][kt], Bf[kt], acc[0][ct], 0, 0, 0);
            acc[1][ct] = __builtin_amdgcn_mfma_f32_16x16x32_bf16(Af[1][kt], Bf[kt], acc[1][ct], 0, 0, 0);
        }
    }
    #pragma unroll
    for (int ct = 0; ct < 8; ++ct) {
        int col = ct * 16 + lr;
        float bv = pb[col];
        #pragma unroll
        for (int rt = 0; rt < 2; ++rt)
            #pragma unroll
            for (int r = 0; r < 4; ++r) {
                float v = acc[rt][ct][r] + bv;
                x1s[wr + rt * 16 + lg * 4 + r][col] = f2bf(v > 0.f ? v : 0.f);
            }
    }
    __syncthreads();

    // ---- GEMM2 ----
    #pragma unroll
    for (int rt = 0; rt < 2; ++rt)
        #pragma unroll
        for (int kt = 0; kt < 4; ++kt)
            Af[rt][kt] = *(const bf16x8*)&x1s[wr + rt * 16 + lr][kt * 32 + lg * 8];
    #pragma unroll
    for (int rt = 0; rt < 2; ++rt)
        #pragma unroll
        for (int ct = 0; ct < 8; ++ct)
            acc[rt][ct] = (f32x4){0.f, 0.f, 0.f, 0.f};
    #pragma unroll
    for (int ct = 0; ct < 8; ++ct) {
        bf16x8 Bf[4];
        #pragma unroll
        for (int kt = 0; kt < 4; ++kt)
            Bf[kt] = *(const bf16x8*)&W1t[(ct * 16 + lr) * 128 + kt * 32 + lg * 8];
        #pragma unroll
        for (int kt = 0; kt < 4; ++kt) {
            acc[0][ct] = __builtin_amdgcn_mfma_f32_16x16x32_bf16(Af[0][kt], Bf[kt], acc[0][ct], 0, 0, 0);
            acc[1][ct] = __builtin_amdgcn_mfma_f32_16x16x32_bf16(Af[1][kt], Bf[kt], acc[1][ct], 0, 0, 0);
        }
    }
    __syncthreads();
    #pragma unroll
    for (int ct = 0; ct < 8; ++ct)
        #pragma unroll
        for (int rt = 0; rt < 2; ++rt)
            #pragma unroll
            for (int r = 0; r < 4; ++r)
                x1s[wr + rt * 16 + lg * 4 + r][ct * 16 + lr] = f2bf(acc[rt][ct][r]);
    __syncthreads();

    // ---- copy out (coalesced) + fused attention dots ----
    #pragma unroll
    for (int i = 0; i < 8; ++i) {
        int idx = tid + i * 256;
        int row = idx >> 4, cc = idx & 15;
        bf16x8 hv = *(const bf16x8*)&x1s[row][cc * 8];
        *(bf16x8*)&h1b[(long)(r0 + row) * 128 + cc * 8] = hv;
        int head = cc >> 2, lc = (cc & 3) * 8;
        float ps = 0.f, pd = 0.f;
        #pragma unroll
        for (int j = 0; j < 8; ++j) {
            float v = (float)hv[j];
            ps += v * attS[head * 32 + lc + j];
            pd += v * attD[head * 32 + lc + j];
        }
        ps += __shfl_xor(ps, 1); ps += __shfl_xor(ps, 2);
        pd += __shfl_xor(pd, 1); pd += __shfl_xor(pd, 2);
        if ((cc & 3) == 0) {
            aS[(r0 + row) * 4 + head] = ps;
            aD[(r0 + row) * 4 + head] = pd;
        }
    }
}

// ================= CSR build: two-level counting sort =================
__global__ void bhist_k(const int* __restrict__ srcA, const int* __restrict__ dstA,
                        int* __restrict__ bcnt_d, int* __restrict__ bcnt_s) {
    __shared__ int hd[NB], hs[NB];
    for (int i = threadIdx.x; i < NB; i += 256) { hd[i] = 0; hs[i] = 0; }
    __syncthreads();
    int e0 = blockIdx.x * CHUNK;
    int e1 = min(e0 + CHUNK, ETOT);
    for (int e = e0 + threadIdx.x; e < e1; e += 256) {
        int s, d;
        if (e < NE) { s = srcA[e]; d = dstA[e]; } else { s = d = e - NE; }
        atomicAdd(&hd[d >> SHIFT], 1);
        atomicAdd(&hs[s >> SHIFT], 1);
    }
    __syncthreads();
    for (int i = threadIdx.x; i < NB; i += 256) {
        if (hd[i]) atomicAdd(&bcnt_d[i], hd[i]);
        if (hs[i]) atomicAdd(&bcnt_s[i], hs[i]);
    }
}

__global__ void bscan_k(const int* __restrict__ bcnt_d, int* __restrict__ boffs_d,
                        int* __restrict__ bcur_d, int* __restrict__ noffs_d,
                        const int* __restrict__ bcnt_s, int* __restrict__ boffs_s,
                        int* __restrict__ bcur_s, int* __restrict__ noffs_s) {
    const int* bcnt = blockIdx.x ? bcnt_s : bcnt_d;
    int* boffs = blockIdx.x ? boffs_s : boffs_d;
    int* bcur  = blockIdx.x ? bcur_s : bcur_d;
    int* noffs = blockIdx.x ? noffs_s : noffs_d;
    __shared__ int v[512];
    int t = threadIdx.x;
    int x = (t < NB) ? bcnt[t] : 0;
    v[t] = x;
    __syncthreads();
    for (int dd = 1; dd < 512; dd <<= 1) {
        int y = (t >= dd) ? v[t - dd] : 0;
        __syncthreads();
        v[t] += y;
        __syncthreads();
    }
    if (t < NB) { int o = v[t] - x; boffs[t] = o; bcur[t] = o; }
    if (t == NB - 1) boffs[NB] = v[t];
    if (t == 0) noffs[NN] = ETOT;
}

__global__ void part_k(const int* __restrict__ srcA, const int* __restrict__ dstA,
                       int* __restrict__ bcur_d, int* __restrict__ bcur_s,
                       int* __restrict__ pr_d, int* __restrict__ pr_s) {
    __shared__ int hd[NB], hs[NB], bd[NB], bs[NB];
    for (int i = threadIdx.x; i < NB; i += 256) { hd[i] = 0; hs[i] = 0; }
    __syncthreads();
    int e0 = blockIdx.x * CHUNK;
    int e1 = min(e0 + CHUNK, ETOT);
    for (int e = e0 + threadIdx.x; e < e1; e += 256) {
        int s, d;
        if (e < NE) { s = srcA[e]; d = dstA[e]; } else { s = d = e - NE; }
        atomicAdd(&hd[d >> SHIFT], 1);
        atomicAdd(&hs[s >> SHIFT], 1);
    }
    __syncthreads();
    for (int i = threadIdx.x; i < NB; i += 256) {
        if (hd[i]) { bd[i] = atomicAdd(&bcur_d[i], hd[i]); hd[i] = 0; }
        if (hs[i]) { bs[i] = atomicAdd(&bcur_s[i], hs[i]); hs[i] = 0; }
    }
    __syncthreads();
    for (int e = e0 + threadIdx.x; e < e1; e += 256) {
        int s, d;
        if (e < NE) { s = srcA[e]; d = dstA[e]; } else { s = d = e - NE; }
        int kd = d >> SHIFT;
        pr_d[bd[kd] + atomicAdd(&hd[kd], 1)] = ((d & (NPB - 1)) << 16) | s;
        int ks = s >> SHIFT;
        pr_s[bs[ks] + atomicAdd(&hs[ks], 1)] = ((s & (NPB - 1)) << 16) | d;
    }
}

__global__ void fine_k(const int* __restrict__ pr_d, const int* __restrict__ boffs_d,
                       int* __restrict__ noffs_d, int* __restrict__ csr_src,
                       const int* __restrict__ pr_s, const int* __restrict__ boffs_s,
                       int* __restrict__ noffs_s, int* __restrict__ csr_dst) {
    const int* pr    = (blockIdx.x < NB) ? pr_d : pr_s;
    const int* boffs = (blockIdx.x < NB) ? boffs_d : boffs_s;
    int* noffs       = (blockIdx.x < NB) ? noffs_d : noffs_s;
    int* csr         = (blockIdx.x < NB) ? csr_src : csr_dst;
    int bkt = (blockIdx.x < NB) ? blockIdx.x : blockIdx.x - NB;
    __shared__ int cnt[NPB], off[NPB];
    int n0 = bkt << SHIFT;
    int base = boffs[bkt], end = boffs[bkt + 1];
    int t = threadIdx.x;
    if (t < NPB) cnt[t] = 0;
    __syncthreads();
    for (int i = base + t; i < end; i += 256)
        atomicAdd(&cnt[pr[i] >> 16], 1);
    __syncthreads();
    if (t < NPB) off[t] = cnt[t];
    __syncthreads();
    for (int dd = 1; dd < NPB; dd <<= 1) {
        int y = 0;
        if (t < NPB && t >= dd) y = off[t - dd];
        __syncthreads();
        if (t < NPB) off[t] += y;
        __syncthreads();
    }
    if (t < NPB) {
        int excl = off[t] - cnt[t];
        int n = n0 + t;
        if (n < NN) noffs[n] = base + excl;
        off[t] = excl;
        cnt[t] = 0;
    }
    __syncthreads();
    for (int i = base + t; i < end; i += 256) {
        int p = pr[i];
        int j = p >> 16;
        int pos = base + off[j] + atomicAdd(&cnt[j], 1);
        csr[pos] = p & 0xFFFF;
    }
}

// --- layer-1: plain-exp softmax + bf16 gather (split-wave) + BN/ELU + att2 dots
__global__ void gather1_k(const int* __restrict__ csr_src, const int* __restrict__ offsets,
                          const float* __restrict__ aS, const float* __restrict__ aD,
                          const unsigned short* __restrict__ h1b, const float* __restrict__ b1,
                          const float* __restrict__ bg, const float* __restrict__ bb,
                          const float* __restrict__ va_s, const float* __restrict__ va_d,
                          unsigned short* __restrict__ x2b, float* __restrict__ aS2,
                          float* __restrict__ aD2) {
    __shared__ float4 wst[4][64];
    __shared__ unsigned sst[4][64];
    int wv = threadIdx.x >> 6;
    int d = (blockIdx.x << 2) + wv;
    if (d >= NN) return;
    int lane = threadIdx.x & 63;
    float4 ad4 = *(const float4*)&aD[d * 4];
    int o0 = offsets[d], o1 = offsets[d + 1];

    // phase A: plain sum of exp per head
    float s0 = 0.f, s1 = 0.f, s2 = 0.f, s3 = 0.f;
    for (int o = o0 + lane; o < o1; o += 64) {
        int s = csr_src[o];
        float4 as4 = *(const float4*)&aS[s * 4];
        s0 += __expf(leaky02(as4.x + ad4.x));
        s1 += __expf(leaky02(as4.y + ad4.y));
        s2 += __expf(leaky02(as4.z + ad4.z));
        s3 += __expf(leaky02(as4.w + ad4.w));
    }
    #pragma unroll
    for (int off = 32; off; off >>= 1) {
        s0 += __shfl_xor(s0, off);
        s1 += __shfl_xor(s1, off);
        s2 += __shfl_xor(s2, off);
        s3 += __shfl_xor(s3, off);
    }
    float i0 = 1.f / (s0 + 1e-16f), i1 = 1.f / (s1 + 1e-16f);
    float i2 = 1.f / (s2 + 1e-16f), i3 = 1.f / (s3 + 1e-16f);

    // phase B: split-wave consume — lanes 0-31 even edges, 32-63 odd edges; 4 cols/lane
    int k = lane & 31, half = lane >> 5;
    unsigned cb = (unsigned)(k * 8);               // byte offset of col 4k
    int headk = k >> 3;
    const char* h1base = (const char*)h1b;
    float a0 = 0.f, a1 = 0.f, a2 = 0.f, a3 = 0.f;
    for (int base = o0; base < o1; base += 64) {
        int e = base + lane;
        if (e < o1) {
            int s = csr_src[e];
            float4 as4 = *(const float4*)&aS[s * 4];
            float4 w;
            w.x = __expf(leaky02(as4.x + ad4.x)) * i0;
            w.y = __expf(leaky02(as4.y + ad4.y)) * i1;
            w.z = __expf(leaky02(as4.z + ad4.z)) * i2;
            w.w = __expf(leaky02(as4.w + ad4.w)) * i3;
            wst[wv][lane] = w;
            sst[wv][lane] = (unsigned)(s << 8);    // row byte offset (256B rows)
        }
        __threadfence_block();
        int nst = min(64, o1 - base);
        for (int t = half; t < nst; t += 2) {
            float w = ((const float*)&wst[wv][t])[headk];
            unsigned ro = sst[wv][t];
            uint2 hv = *(const uint2*)(h1base + ro + cb);
            a0 += w * __uint_as_float(hv.x << 16);
            a1 += w * __uint_as_float(hv.x & 0xFFFF0000u);
            a2 += w * __uint_as_float(hv.y << 16);
            a3 += w * __uint_as_float(hv.y & 0xFFFF0000u);
        }
    }
    // combine the two halves
    a0 += __shfl_xor(a0, 32); a1 += __shfl_xor(a1, 32);
    a2 += __shfl_xor(a2, 32); a3 += __shfl_xor(a3, 32);

    // epilogue: bias + BN + ELU on 4 cols (c0 = 4k)
    int c = k * 4;
    float v0 = (a0 + b1[c])     * BN_K * bg[c]     + bb[c];
    float v1 = (a1 + b1[c + 1]) * BN_K * bg[c + 1] + bb[c + 1];
    float v2 = (a2 + b1[c + 2]) * BN_K * bg[c + 2] + bb[c + 2];
    float v3 = (a3 + b1[c + 3]) * BN_K * bg[c + 3] + bb[c + 3];
    v0 = v0 > 0.f ? v0 : __expf(v0) - 1.f;
    v1 = v1 > 0.f ? v1 : __expf(v1) - 1.f;
    v2 = v2 > 0.f ? v2 : __expf(v2) - 1.f;
    v3 = v3 > 0.f ? v3 : __expf(v3) - 1.f;
    if (half == 0) {
        uint2 pk;
        pk.x = (unsigned)f2bf(v0) | ((unsigned)f2bf(v1) << 16);
        pk.y = (unsigned)f2bf(v2) | ((unsigned)f2bf(v3) << 16);
        *(uint2*)&x2b[(long)d * 128 + c] = pk;
    }

    // fused layer-2 attention dots (lower half contributes, full-wave reduce)
    float r[8];
    #pragma unroll
    for (int h = 0; h < 4; ++h) {
        float4 vs = *(const float4*)&va_s[h * 128 + c];
        float4 vd = *(const float4*)&va_d[h * 128 + c];
        float rs = v0 * vs.x + v1 * vs.y + v2 * vs.z + v3 * vs.w;
        float rd = v0 * vd.x + v1 * vd.y + v2 * vd.z + v3 * vd.w;
        r[h]     = half ? 0.f : rs;
        r[4 + h] = half ? 0.f : rd;
    }
    #pragma unroll
    for (int off = 32; off; off >>= 1) {
        #pragma unroll
        for (int j = 0; j < 8; ++j) r[j] += __shfl_xor(r[j], off);
    }
    if (lane == 0) {
        *(float4*)&aS2[d * 4] = make_float4(r[0], r[1], r[2], r[3]);
        *(float4*)&aD2[d * 4] = make_float4(r[4], r[5], r[6], r[7]);
    }
}

// ---------------- layer-2 folding: va = W2^T att2 ----------------
__global__ void fold_k(const float* __restrict__ W2, const float* __restrict__ as2,
                       const float* __restrict__ ad2, float* __restrict__ va_s,
                       float* __restrict__ va_d) {
    int h = blockIdx.x;
    int k = threadIdx.x;
    const float* wrow = W2 + (long)k * 512 + h * 128;
    float accs = 0.f, accd = 0.f;
    for (int ci = 0; ci < 128; ++ci) {
        float w = wrow[ci];
        accs += w * as2[h * 128 + ci];
        accd += w * ad2[h * 128 + ci];
    }
    va_s[h * 128 + k] = accs;
    va_d[h * 128 + k] = accd;
}

// ---- layer-2: per-dst sum of exp -> adL = {ad4, invS4} ------
__global__ void dsum_k(const int* __restrict__ csr_src, const int* __restrict__ offsets,
                       const float* __restrict__ aS, const float* __restrict__ aD,
                       float* __restrict__ adL) {
    int d = (blockIdx.x << 2) + (threadIdx.x >> 6);
    if (d >= NN) return;
    int lane = threadIdx.x & 63;
    float4 ad4 = *(const float4*)&aD[d * 4];
    int o0 = offsets[d], o1 = offsets[d + 1];
    float s0 = 0.f, s1 = 0.f, s2 = 0.f, s3 = 0.f;
    for (int o = o0 + lane; o < o1; o += 64) {
        int s = csr_src[o];
        float4 as4 = *(const float4*)&aS[s * 4];
        s0 += __expf(leaky02(as4.x + ad4.x));
        s1 += __expf(leaky02(as4.y + ad4.y));
        s2 += __expf(leaky02(as4.z + ad4.z));
        s3 += __expf(leaky02(as4.w + ad4.w));
    }
    #pragma unroll
    for (int off = 32; off; off >>= 1) {
        s0 += __shfl_xor(s0, off);
        s1 += __shfl_xor(s1, off);
        s2 += __shfl_xor(s2, off);
        s3 += __shfl_xor(s3, off);
    }
    if (lane == 0) {
        *(float4*)&adL[d * 8]     = ad4;
        *(float4*)&adL[d * 8 + 4] = make_float4(1.f / (s0 + 1e-16f), 1.f / (s1 + 1e-16f),
                                                1.f / (s2 + 1e-16f), 1.f / (s3 + 1e-16f));
    }
}

// ---------------- layer-2: per-src weight via src-CSR ----------------
__global__ void waccg_k(const int* __restrict__ csr_dst, const int* __restrict__ offsetsS,
                        const float* __restrict__ aS, const float* __restrict__ adL,
                        float* __restrict__ Wacc) {
    int s = (blockIdx.x << 2) + (threadIdx.x >> 6);
    if (s >= NN) return;
    int lane = threadIdx.x & 63;
    float4 as4 = *(const float4*)&aS[s * 4];
    int o0 = offsetsS[s], o1 = offsetsS[s + 1];
    float a0 = 0.f, a1 = 0.f, a2 = 0.f, a3 = 0.f;
    for (int o = o0 + lane; o < o1; o += 64) {
        int d = csr_dst[o];
        float4 ad4 = *(const float4*)&adL[d * 8];
        float4 iv  = *(const float4*)&adL[d * 8 + 4];
        a0 += __expf(leaky02(as4.x + ad4.x)) * iv.x;
        a1 += __expf(leaky02(as4.y + ad4.y)) * iv.y;
        a2 += __expf(leaky02(as4.z + ad4.z)) * iv.z;
        a3 += __expf(leaky02(as4.w + ad4.w)) * iv.w;
    }
    #pragma unroll
    for (int off = 32; off; off >>= 1) {
        a0 += __shfl_xor(a0, off);
        a1 += __shfl_xor(a1, off);
        a2 += __shfl_xor(a2, off);
        a3 += __shfl_xor(a3, off);
    }
    if (lane == 0) {
        const float scale = 0.25f / (float)NN;
        *(float4*)&Wacc[s * 4] = make_float4(scale * a0, scale * a1, scale * a2, scale * a3);
    }
}

// y[h,k] = sum_r Wacc[r,h] * x2[r,k]  (x2 in bf16)
__global__ void yacc_k(const float* __restrict__ Wacc, const unsigned short* __restrict__ x2b,
                       float* __restrict__ y) {
    int k2 = threadIdx.x;
    float a[8] = {};
    for (int r = blockIdx.x; r < NN; r += gridDim.x) {
        float4 w = *(const float4*)&Wacc[r * 4];
        unsigned hv = *(const unsigned*)&x2b[(long)r * 128 + k2 * 2];
        float xl = __uint_as_float(hv << 16);
        float xh = __uint_as_float(hv & 0xFFFF0000u);
        a[0] += w.x * xl; a[1] += w.x * xh;
        a[2] += w.y * xl; a[3] += w.y * xh;
        a[4] += w.z * xl; a[5] += w.z * xh;
        a[6] += w.w * xl; a[7] += w.w * xh;
    }
    int c = k2 * 2;
    atomicAdd(&y[0 * 128 + c], a[0]); atomicAdd(&y[0 * 128 + c + 1], a[1]);
    atomicAdd(&y[1 * 128 + c], a[2]); atomicAdd(&y[1 * 128 + c + 1], a[3]);
    atomicAdd(&y[2 * 128 + c], a[4]); atomicAdd(&y[2 * 128 + c + 1], a[5]);
    atomicAdd(&y[3 * 128 + c], a[6]); atomicAdd(&y[3 * 128 + c + 1], a[7]);
}

__global__ void final2_k(const float* __restrict__ y, const float* __restrict__ W2,
                         const float* __restrict__ b2, const float* __restrict__ oW,
                         const float* __restrict__ ob, float* __restrict__ out) {
    __shared__ float xm[128];
    int c = threadIdx.x;
    float t = b2[c];
    #pragma unroll
    for (int h = 0; h < 4; ++h) {
        const float* yh = y + h * 128;
        for (int k = 0; k < 128; ++k) t += yh[k] * W2[(long)k * 512 + h * 128 + c];
    }
    xm[c] = t;
    __syncthreads();
    float acc = ob[c];
    for (int k = 0; k < 128; ++k) acc += xm[k] * oW[k * 128 + c];
    out[c] = acc > 0.f ? acc : 0.f;
}

extern "C" void kernel_launch(void* const* d_in, const int* in_sizes, int n_in,
                              void* d_out, int out_size, void* d_ws, size_t ws_size,
                              hipStream_t stream) {
    const float* x0  = (const float*)d_in[0];
    const int*   ei  = (const int*)d_in[1];
    const float* pW  = (const float*)d_in[2];
    const float* pb  = (const float*)d_in[3];
    const float* W1  = (const float*)d_in[4];
    const float* as1 = (const float*)d_in[5];
    const float* ad1 = (const float*)d_in[6];
    const float* b1  = (const float*)d_in[7];
    const float* bg  = (const float*)d_in[8];
    const float* bb  = (const float*)d_in[9];
    const float* W2  = (const float*)d_in[10];
    const float* as2 = (const float*)d_in[11];
    const float* ad2 = (const float*)d_in[12];
    const float* b2  = (const float*)d_in[13];
    const float* oW  = (const float*)d_in[14];
    const float* ob  = (const float*)d_in[15];
    float* out = (float*)d_out;

    float* ws = (float*)d_ws;
    unsigned short* x0b = (unsigned short*)ws; ws += 3203072;
    unsigned short* h1b = (unsigned short*)ws; ws += 3203072;
    unsigned short* x2b = (unsigned short*)ws; ws += 3200000;
    unsigned short* pWt = (unsigned short*)ws; ws += 8192;
    unsigned short* W1t = (unsigned short*)ws; ws += 8192;
    float* aS1   = ws; ws += 200192;
    float* aD1   = ws; ws += 200192;
    float* aS2   = ws; ws += 200000;
    float* aD2   = ws; ws += 200000;
    float* adL   = ws; ws += 400000;
    float* Wacc  = ws; ws += 200000;
    float* va_s  = ws; ws += 512;
    float* va_d  = ws; ws += 512;
    float* y     = ws; ws += 512;
    int* bcnt_d  = (int*)ws; ws += NB;
    int* boffs_d = (int*)ws; ws += NB + 1;
    int* bcur_d  = (int*)ws; ws += NB;
    int* bcnt_s  = (int*)ws; ws += NB;
    int* boffs_s = (int*)ws; ws += NB + 1;
    int* bcur_s  = (int*)ws; ws += NB;
    int* offs_d  = (int*)ws; ws += NN + 1;
    int* offs_s  = (int*)ws; ws += NN + 1;
    int* csr_src = (int*)ws; ws += ETOT;
    int* csr_dst = (int*)ws; ws += ETOT;
    int* pr_d    = (int*)ws; ws += ETOT;
    int* pr_s    = (int*)ws; ws += ETOT;

    const int* srcA = ei;
    const int* dstA = ei + NE;

    hipMemsetAsync(bcnt_d, 0, (size_t)NB * 4, stream);
    hipMemsetAsync(bcnt_s, 0, (size_t)NB * 4, stream);
    hipMemsetAsync(y, 0, (size_t)512 * 4, stream);

    dim3 blk(256);

    // prep + CSR (independent of dense chain)
    cvt_k<<<(NROW * 32 + 255) / 256, blk, 0, stream>>>(x0, x0b);
    prepw_k<<<2, blk, 0, stream>>>(pW, W1, pWt, W1t);
    bhist_k<<<PGRID, blk, 0, stream>>>(srcA, dstA, bcnt_d, bcnt_s);
    bscan_k<<<2, 512, 0, stream>>>(bcnt_d, boffs_d, bcur_d, offs_d,
                                   bcnt_s, boffs_s, bcur_s, offs_s);
    part_k<<<PGRID, blk, 0, stream>>>(srcA, dstA, bcur_d, bcur_s, pr_d, pr_s);
    fine_k<<<2 * NB, blk, 0, stream>>>(pr_d, boffs_d, offs_d, csr_src,
                                       pr_s, boffs_s, offs_s, csr_dst);

    // fused dense chain (MFMA bf16)
    fgemm_k<<<391, blk, 0, stream>>>(x0b, pWt, W1t, pb, as1, ad1, h1b, aS1, aD1);
    fold_k<<<4, 128, 0, stream>>>(W2, as2, ad2, va_s, va_d);

    // layer-1 aggregation + fused layer-2 att dots
    gather1_k<<<12500, blk, 0, stream>>>(csr_src, offs_d, aS1, aD1, h1b, b1, bg, bb,
                                         va_s, va_d, x2b, aS2, aD2);

    // layer 2 (h2 never materialized)
    dsum_k<<<12500, blk, 0, stream>>>(csr_src, offs_d, aS2, aD2, adL);
    waccg_k<<<12500, blk, 0, stream>>>(csr_dst, offs_s, aS2, adL, Wacc);
    yacc_k<<<256, 64, 0, stream>>>(Wacc, x2b, y);
    final2_k<<<1, 128, 0, stream>>>(y, W2, b2, oW, ob, out);
}